// Round 3
// baseline (2647.470 us; speedup 1.0000x reference)
//
#include <hip/hip_runtime.h>
#include <hip/hip_bf16.h>

#define NVOC 50257
#define DIM 256
#define HID 256
#define NLAYER 2
#define SEQ 128
#define BATCH 16
#define SENT 0xFFFFFFFFu

typedef __bf16 bf16x8 __attribute__((ext_vector_type(8)));
typedef float f32x4 __attribute__((ext_vector_type(4)));
typedef unsigned short u16;
typedef unsigned int u32;
typedef u32 u32x4v __attribute__((ext_vector_type(4)));

#define AL(p)   __hip_atomic_load((p), __ATOMIC_RELAXED, __HIP_MEMORY_SCOPE_AGENT)
#define AS(p,v) __hip_atomic_store((p), (v), __ATOMIC_RELAXED, __HIP_MEMORY_SCOPE_AGENT)

// ---------------- prep: dec_w f32 -> bf16 ----------------
__global__ void prep_kernel(const float* __restrict__ dw, u16* __restrict__ dwb, int n4) {
  int tid = blockIdx.x * blockDim.x + threadIdx.x;
  int stride = gridDim.x * blockDim.x;
  for (int i = tid; i < n4; i += stride) {
    float4 v = reinterpret_cast<const float4*>(dw)[i];
    ushort4 o;
    o.x = __builtin_bit_cast(u16, (__bf16)v.x);
    o.y = __builtin_bit_cast(u16, (__bf16)v.y);
    o.z = __builtin_bit_cast(u16, (__bf16)v.z);
    o.w = __builtin_bit_cast(u16, (__bf16)v.w);
    reinterpret_cast<ushort4*>(dwb)[i] = o;
  }
}

// ---------------- XU precompute + sentinel fill ----------------
// XU[t*16+b][g*256+c] = emb[tok[t,b]] @ U_g. Grid (32,4) x 256.
__global__ __launch_bounds__(256) void xu_kernel(
    const int* __restrict__ tokp, const float* __restrict__ embp,
    const float* __restrict__ uF, const float* __restrict__ uI,
    const float* __restrict__ uC, const float* __restrict__ uO,
    float* __restrict__ XU, u32* __restrict__ hsent)
{
  const int tid = threadIdx.x;
  // sentinel-fill h0b+h1b (contiguous): SEQ*BATCH*HID u32 words
  {
    const int nthreads = 32 * 4 * 256;
    int g = (blockIdx.y * gridDim.x + blockIdx.x) * blockDim.x + tid;
    for (int i = g; i < SEQ * BATCH * HID; i += nthreads) hsent[i] = SENT;
  }

  const int lane = tid & 63, wv = tid >> 6, r16 = lane & 15, kgrp = lane >> 4;
  const int m0 = blockIdx.x * 64;
  const int n0 = blockIdx.y * 256 + wv * 64;
  const float* Ug[4] = {uF, uI, uC, uO};

  bf16x8 b[4][8];
#pragma unroll
  for (int nt = 0; nt < 4; ++nt) {
    const int n = n0 + nt * 16 + r16;
    const float* U = Ug[n >> 8];
    const int c = n & 255;
#pragma unroll
    for (int kk = 0; kk < 8; ++kk) {
      const int kb = kk * 32 + kgrp * 8;
      bf16x8 v;
#pragma unroll
      for (int e = 0; e < 8; ++e) v[e] = (__bf16)U[(size_t)(kb + e) * HID + c];
      b[nt][kk] = v;
    }
  }

  for (int mi = 0; mi < 4; ++mi) {
    const int tok = tokp[m0 + mi * 16 + r16];
    const float* x = embp + (size_t)tok * DIM;
    bf16x8 a[8];
#pragma unroll
    for (int kk = 0; kk < 8; ++kk) {
      const int kb = kk * 32 + kgrp * 8;
      const float4 u0 = *reinterpret_cast<const float4*>(x + kb);
      const float4 u1 = *reinterpret_cast<const float4*>(x + kb + 4);
      bf16x8 v;
      v[0] = (__bf16)u0.x; v[1] = (__bf16)u0.y; v[2] = (__bf16)u0.z; v[3] = (__bf16)u0.w;
      v[4] = (__bf16)u1.x; v[5] = (__bf16)u1.y; v[6] = (__bf16)u1.z; v[7] = (__bf16)u1.w;
      a[kk] = v;
    }
#pragma unroll
    for (int nt = 0; nt < 4; ++nt) {
      f32x4 acc = {0.f, 0.f, 0.f, 0.f};
#pragma unroll
      for (int kk = 0; kk < 8; ++kk)
        acc = __builtin_amdgcn_mfma_f32_16x16x32_bf16(a[kk], b[nt][kk], acc, 0, 0, 0);
      const int n = n0 + nt * 16 + r16;
#pragma unroll
      for (int r = 0; r < 4; ++r)
        XU[(size_t)(m0 + mi * 16 + kgrp * 4 + r) * 1024 + n] = acc[r];
    }
  }
}

// ---------------- persistent LSTM, data-as-flag sync ----------------
// 12 WGs x 512 thr. bx 0..3: layer 0, 64 cols/gate. bx 4..11: layer 1, 32 cols/gate.
// h stored as packed bf16-pair u32 relaxed-agent atomics; consumers poll their
// exact input words against the NaN sentinel. No fences, no flags.
__global__ __launch_bounds__(512, 1) void lstm_kernel(
    const float* __restrict__ wF, const float* __restrict__ bF,
    const float* __restrict__ wI, const float* __restrict__ bI,
    const float* __restrict__ wC, const float* __restrict__ bC,
    const float* __restrict__ wO, const float* __restrict__ bO,
    const float* __restrict__ uF, const float* __restrict__ uI,
    const float* __restrict__ uC, const float* __restrict__ uO,
    const float* __restrict__ XU, u16* __restrict__ h0b, u16* __restrict__ h1b,
    float* __restrict__ dout)
{
  const int tid  = threadIdx.x;
  const int lane = tid & 63;
  const int wv   = tid >> 6;
  const int bx   = blockIdx.x;
  const int gate = wv >> 1;
  const int hf   = wv & 1;
  const int r16  = lane & 15;
  const int kgrp = lane >> 4;

  const float* Wg[4] = {wF, wI, wC, wO};
  const float* Ug[4] = {uF, uI, uC, uO};
  const float* Bg[4] = {bF, bI, bC, bO};

  __shared__ float gbuf[4][16][66];

  u32* h0w = reinterpret_cast<u32*>(h0b);
  u32* h1w = reinterpret_cast<u32*>(h1b);
  const size_t logitsN = (size_t)SEQ * BATCH * NVOC;
  const int eb = tid >> 5;

  if (bx < 4) {
    // ================= layer 0 =================
    const int jj = bx;
    bf16x8 bw[2][8];
    float bias[2];
#pragma unroll
    for (int nt = 0; nt < 2; ++nt) {
      const int n = jj * 64 + hf * 32 + nt * 16 + r16;
      bias[nt] = Bg[gate][n];
#pragma unroll
      for (int kk = 0; kk < 8; ++kk) {
        const int kb = kk * 32 + kgrp * 8;
        bf16x8 v;
#pragma unroll
        for (int e = 0; e < 8; ++e) v[e] = (__bf16)Wg[gate][(size_t)(kb + e) * HID + n];
        bw[nt][kk] = v;
      }
    }
    const int ncol0 = gate * 256 + jj * 64 + hf * 32 + r16;
    float c0 = 0.f, c1 = 0.f;

    for (int t = 0; t < SEQ; ++t) {
      float xu0[4], xu1[4];
      const float* xp = XU + (size_t)t * BATCH * 1024;
#pragma unroll
      for (int r = 0; r < 4; ++r) {
        xu0[r] = xp[(size_t)(kgrp * 4 + r) * 1024 + ncol0];
        xu1[r] = xp[(size_t)(kgrp * 4 + r) * 1024 + ncol0 + 16];
      }

      f32x4 acc0 = {0.f, 0.f, 0.f, 0.f};
      f32x4 acc1 = {0.f, 0.f, 0.f, 0.f};
      if (t > 0) {
        const u32* b0 = h0w + ((size_t)(t - 1) * BATCH + r16) * 128 + kgrp * 4;
        u32 w[8][4];
        bool ok;
        do {
          ok = true;
#pragma unroll
          for (int kk = 0; kk < 8; ++kk)
#pragma unroll
            for (int j = 0; j < 4; ++j) {
              w[kk][j] = AL(b0 + kk * 16 + j);
              ok = ok && (w[kk][j] != SENT);
            }
        } while (!__all(ok));
#pragma unroll
        for (int kk = 0; kk < 8; ++kk) {
          u32x4v v = {w[kk][0], w[kk][1], w[kk][2], w[kk][3]};
          bf16x8 a = __builtin_bit_cast(bf16x8, v);
          acc0 = __builtin_amdgcn_mfma_f32_16x16x32_bf16(a, bw[0][kk], acc0, 0, 0, 0);
          acc1 = __builtin_amdgcn_mfma_f32_16x16x32_bf16(a, bw[1][kk], acc1, 0, 0, 0);
        }
      }

#pragma unroll
      for (int nt = 0; nt < 2; ++nt) {
        const f32x4 acc = nt ? acc1 : acc0;
        const float* xu = nt ? xu1 : xu0;
        const int c = hf * 32 + nt * 16 + r16;
#pragma unroll
        for (int r = 0; r < 4; ++r) {
          const float z = acc[r] + bias[nt] + xu[r];
          gbuf[gate][kgrp * 4 + r][c] = (gate == 2) ? tanhf(z) : 1.f / (1.f + expf(-z));
        }
      }
      __syncthreads();

      const int ec = (tid & 31) * 2;
      const float ff0 = gbuf[0][eb][ec], ff1 = gbuf[0][eb][ec + 1];
      const float ii0 = gbuf[1][eb][ec], ii1 = gbuf[1][eb][ec + 1];
      const float gg0 = gbuf[2][eb][ec], gg1 = gbuf[2][eb][ec + 1];
      const float oo0 = gbuf[3][eb][ec], oo1 = gbuf[3][eb][ec + 1];
      c0 = ff0 * c0 + ii0 * gg0;
      c1 = ff1 * c1 + ii1 * gg1;
      const float hv0 = oo0 * tanhf(c0);
      const float hv1 = oo1 * tanhf(c1);
      const u32 pk = (u32)__builtin_bit_cast(u16, (__bf16)hv0) |
                     ((u32)__builtin_bit_cast(u16, (__bf16)hv1) << 16);
      AS(h0w + ((size_t)t * BATCH + eb) * 128 + jj * 32 + (tid & 31), pk);
      if (t == SEQ - 1) {
        const int n = jj * 64 + ec;
        float* hT = dout + logitsN + (size_t)eb * HID + n;
        float* cT = dout + logitsN + (size_t)NLAYER * BATCH * HID + (size_t)eb * HID + n;
        hT[0] = hv0; hT[1] = hv1;
        cT[0] = c0;  cT[1] = c1;
      }
      __syncthreads();
    }
  } else {
    // ================= layer 1 =================
    const int jj = bx - 4;  // 0..7, 32 cols/gate
    const int n = jj * 32 + hf * 16 + r16;
    const float bias = Bg[gate][n];
    bf16x8 bw[16];
#pragma unroll
    for (int kk = 0; kk < 8; ++kk) {
      const int kb = kk * 32 + kgrp * 8;
      bf16x8 v, u;
#pragma unroll
      for (int e = 0; e < 8; ++e) {
        v[e] = (__bf16)Wg[gate][(size_t)(kb + e) * HID + n];
        u[e] = (__bf16)Ug[gate][(size_t)(kb + e) * HID + n];
      }
      bw[kk] = v;
      bw[kk + 8] = u;
    }
    float c0 = 0.f, c1 = 0.f;

    for (int t = 0; t < SEQ; ++t) {
      const u32* b0 = h0w + ((size_t)t * BATCH + r16) * 128 + kgrp * 4;
      u32 w0[8][4], w1[8][4];
      bool ok;
      if (t > 0) {
        const u32* b1 = h1w + ((size_t)(t - 1) * BATCH + r16) * 128 + kgrp * 4;
        do {
          ok = true;
#pragma unroll
          for (int kk = 0; kk < 8; ++kk)
#pragma unroll
            for (int j = 0; j < 4; ++j) {
              w1[kk][j] = AL(b1 + kk * 16 + j);
              ok = ok && (w1[kk][j] != SENT);
              w0[kk][j] = AL(b0 + kk * 16 + j);
              ok = ok && (w0[kk][j] != SENT);
            }
        } while (!__all(ok));
      } else {
        do {
          ok = true;
#pragma unroll
          for (int kk = 0; kk < 8; ++kk)
#pragma unroll
            for (int j = 0; j < 4; ++j) {
              w0[kk][j] = AL(b0 + kk * 16 + j);
              ok = ok && (w0[kk][j] != SENT);
            }
        } while (!__all(ok));
      }

      f32x4 acc = {0.f, 0.f, 0.f, 0.f};
      if (t > 0) {
#pragma unroll
        for (int kk = 0; kk < 8; ++kk) {
          u32x4v v = {w1[kk][0], w1[kk][1], w1[kk][2], w1[kk][3]};
          bf16x8 a = __builtin_bit_cast(bf16x8, v);
          acc = __builtin_amdgcn_mfma_f32_16x16x32_bf16(a, bw[kk], acc, 0, 0, 0);
        }
      }
#pragma unroll
      for (int kk = 0; kk < 8; ++kk) {
        u32x4v v = {w0[kk][0], w0[kk][1], w0[kk][2], w0[kk][3]};
        bf16x8 a = __builtin_bit_cast(bf16x8, v);
        acc = __builtin_amdgcn_mfma_f32_16x16x32_bf16(a, bw[kk + 8], acc, 0, 0, 0);
      }

      {
        const int c = hf * 16 + r16;
#pragma unroll
        for (int r = 0; r < 4; ++r) {
          const float z = acc[r] + bias;
          gbuf[gate][kgrp * 4 + r][c] = (gate == 2) ? tanhf(z) : 1.f / (1.f + expf(-z));
        }
      }
      __syncthreads();

      if ((tid & 31) < 16) {
        const int p = tid & 15;
        const int ec = p * 2;
        const float ff0 = gbuf[0][eb][ec], ff1 = gbuf[0][eb][ec + 1];
        const float ii0 = gbuf[1][eb][ec], ii1 = gbuf[1][eb][ec + 1];
        const float gg0 = gbuf[2][eb][ec], gg1 = gbuf[2][eb][ec + 1];
        const float oo0 = gbuf[3][eb][ec], oo1 = gbuf[3][eb][ec + 1];
        c0 = ff0 * c0 + ii0 * gg0;
        c1 = ff1 * c1 + ii1 * gg1;
        const float hv0 = oo0 * tanhf(c0);
        const float hv1 = oo1 * tanhf(c1);
        const u32 pk = (u32)__builtin_bit_cast(u16, (__bf16)hv0) |
                       ((u32)__builtin_bit_cast(u16, (__bf16)hv1) << 16);
        AS(h1w + ((size_t)t * BATCH + eb) * 128 + jj * 16 + p, pk);
        if (t == SEQ - 1) {
          const int nn = jj * 32 + ec;
          float* hT = dout + logitsN + (size_t)(BATCH + eb) * HID + nn;
          float* cT = dout + logitsN + (size_t)NLAYER * BATCH * HID +
                      (size_t)(BATCH + eb) * HID + nn;
          hT[0] = hv0; hT[1] = hv1;
          cT[0] = c0;  cT[1] = c1;
        }
      }
      __syncthreads();
    }
  }
}

// ---------------- decoder: logits = h_top @ dec_w^T + dec_b ----------------
__global__ __launch_bounds__(256) void dec_kernel(
    const u16* __restrict__ htb, const u16* __restrict__ dwb,
    const float* __restrict__ dbp, float* __restrict__ out)
{
  const int tid  = threadIdx.x;
  const int lane = tid & 63;
  const int wv   = tid >> 6;
  const int r16  = lane & 15;
  const int kgrp = lane >> 4;
  const int m0 = blockIdx.x * 32;
  const int n0 = blockIdx.y * 256 + wv * 64;

  bf16x8 a[2][8];
#pragma unroll
  for (int mt = 0; mt < 2; ++mt) {
    const u16* ap = htb + ((size_t)(m0 + mt * 16 + r16)) * HID + kgrp * 8;
#pragma unroll
    for (int kk = 0; kk < 8; ++kk)
      a[mt][kk] = *reinterpret_cast<const bf16x8*>(ap + kk * 32);
  }

  f32x4 acc[2][4];
#pragma unroll
  for (int mt = 0; mt < 2; ++mt)
#pragma unroll
    for (int nt = 0; nt < 4; ++nt) {
      acc[mt][nt][0] = 0.f; acc[mt][nt][1] = 0.f;
      acc[mt][nt][2] = 0.f; acc[mt][nt][3] = 0.f;
    }

#pragma unroll
  for (int nt = 0; nt < 4; ++nt) {
    const int v = n0 + nt * 16 + r16;
    const int vc = (v < NVOC) ? v : 0;
    const u16* bp = dwb + (size_t)vc * HID + kgrp * 8;
#pragma unroll
    for (int kk = 0; kk < 8; ++kk) {
      const bf16x8 b = *reinterpret_cast<const bf16x8*>(bp + kk * 32);
      acc[0][nt] = __builtin_amdgcn_mfma_f32_16x16x32_bf16(a[0][kk], b, acc[0][nt], 0, 0, 0);
      acc[1][nt] = __builtin_amdgcn_mfma_f32_16x16x32_bf16(a[1][kk], b, acc[1][nt], 0, 0, 0);
    }
  }

#pragma unroll
  for (int nt = 0; nt < 4; ++nt) {
    const int v = n0 + nt * 16 + r16;
    if (v < NVOC) {
      const float bb = dbp[v];
#pragma unroll
      for (int mt = 0; mt < 2; ++mt)
#pragma unroll
        for (int r = 0; r < 4; ++r)
          out[(size_t)(m0 + mt * 16 + kgrp * 4 + r) * NVOC + v] = acc[mt][nt][r] + bb;
    }
  }
}

extern "C" void kernel_launch(void* const* d_in, const int* in_sizes, int n_in,
                              void* d_out, int out_size, void* d_ws, size_t ws_size,
                              hipStream_t stream) {
  const int*   tokp = (const int*)d_in[0];
  const float* embp = (const float*)d_in[1];
  const float* wF = (const float*)d_in[2];
  const float* uF = (const float*)d_in[3];
  const float* bF = (const float*)d_in[4];
  const float* wI = (const float*)d_in[5];
  const float* uI = (const float*)d_in[6];
  const float* bI = (const float*)d_in[7];
  const float* wC = (const float*)d_in[8];
  const float* uC = (const float*)d_in[9];
  const float* bC = (const float*)d_in[10];
  const float* wO = (const float*)d_in[11];
  const float* uO = (const float*)d_in[12];
  const float* bO = (const float*)d_in[13];
  const float* dw = (const float*)d_in[14];
  const float* db = (const float*)d_in[15];
  float* out = (float*)d_out;

  char* ws = (char*)d_ws;
  size_t off = 0;
  // region A: XU (8 MB, alive during lstm) aliased with dwb (25.7 MB, alive during dec)
  char* regionA = ws;
  off += (size_t)NVOC * HID * 2;
  off = (off + 255) & ~(size_t)255;
  u16* h0b = (u16*)(ws + off); off += (size_t)SEQ * BATCH * HID * 2;
  u16* h1b = (u16*)(ws + off); off += (size_t)SEQ * BATCH * HID * 2;

  float* XU  = (float*)regionA;
  u16*   dwb = (u16*)regionA;

  // xu (writes XU + sentinel-fills h0b/h1b) -> lstm (reads XU) ->
  // prep (overwrites region A with dwb) -> dec (reads dwb, h1b)
  xu_kernel<<<dim3(32, 4), 256, 0, stream>>>(tokp, embp, uF, uI, uC, uO, XU, (u32*)h0b);
  lstm_kernel<<<12, 512, 0, stream>>>(wF, bF, wI, bI, wC, bC, wO, bO,
                                      uF, uI, uC, uO, XU, h0b, h1b, out);
  prep_kernel<<<1024, 256, 0, stream>>>(dw, dwb, NVOC * HID / 4);
  dec_kernel<<<dim3(64, (NVOC + 255) / 256), 256, 0, stream>>>(h1b, dwb, db, out);
}

// Round 5
// 1580.144 us; speedup vs baseline: 1.6755x; 1.6755x over previous
//
#include <hip/hip_runtime.h>
#include <hip/hip_bf16.h>

#define NVOC 50257
#define DIM 256
#define HID 256
#define NLAYER 2
#define SEQ 128
#define BATCH 16
#define SENT 0xFFFFFFFFu
#define GUARD (1 << 21)

typedef __bf16 bf16x8 __attribute__((ext_vector_type(8)));
typedef float f32x4 __attribute__((ext_vector_type(4)));
typedef unsigned short u16;
typedef unsigned int u32;
typedef unsigned long long u64;
typedef u32 u32x4v __attribute__((ext_vector_type(4)));

#define AL32(p)   __hip_atomic_load((const u32*)(p), __ATOMIC_RELAXED, __HIP_MEMORY_SCOPE_AGENT)
#define AL64(p)   __hip_atomic_load((const u64*)(p), __ATOMIC_RELAXED, __HIP_MEMORY_SCOPE_AGENT)
#define AS32(p,v) __hip_atomic_store((u32*)(p), (v), __ATOMIC_RELAXED, __HIP_MEMORY_SCOPE_AGENT)
#define AS64(p,v) __hip_atomic_store((u64*)(p), (v), __ATOMIC_RELAXED, __HIP_MEMORY_SCOPE_AGENT)

// ---------------- prep: dec_w f32 -> bf16 ----------------
__global__ void prep_kernel(const float* __restrict__ dw, u16* __restrict__ dwb, int n4) {
  int tid = blockIdx.x * blockDim.x + threadIdx.x;
  int stride = gridDim.x * blockDim.x;
  for (int i = tid; i < n4; i += stride) {
    float4 v = reinterpret_cast<const float4*>(dw)[i];
    ushort4 o;
    o.x = __builtin_bit_cast(u16, (__bf16)v.x);
    o.y = __builtin_bit_cast(u16, (__bf16)v.y);
    o.z = __builtin_bit_cast(u16, (__bf16)v.z);
    o.w = __builtin_bit_cast(u16, (__bf16)v.w);
    reinterpret_cast<ushort4*>(dwb)[i] = o;
  }
}

// ---------------- XU precompute + sentinel fill + flag zero ----------------
// XU[t*16+b][g*256+c] = emb[tok[t,b]] @ U_g. Grid (32,4) x 256.
__global__ __launch_bounds__(256) void xu_kernel(
    const int* __restrict__ tokp, const float* __restrict__ embp,
    const float* __restrict__ uF, const float* __restrict__ uI,
    const float* __restrict__ uC, const float* __restrict__ uO,
    float* __restrict__ XU, u32* __restrict__ hz, u32* __restrict__ flg)
{
  const int tid = threadIdx.x;
  {
    const int nthreads = 32 * 4 * 256;
    const int g = (blockIdx.y * gridDim.x + blockIdx.x) * blockDim.x + tid;
    for (int i = g; i < SEQ * BATCH * HID; i += nthreads) hz[i] = SENT;  // h0w+h1w
    if (blockIdx.x == 0 && blockIdx.y == 0)
      for (int i = tid; i < SEQ * 8; i += 256) flg[i] = 0u;
  }

  const int lane = tid & 63, wv = tid >> 6, r16 = lane & 15, kgrp = lane >> 4;
  const int m0 = blockIdx.x * 64;
  const int n0 = blockIdx.y * 256 + wv * 64;
  const float* Ug[4] = {uF, uI, uC, uO};

  bf16x8 b[4][8];
#pragma unroll
  for (int nt = 0; nt < 4; ++nt) {
    const int n = n0 + nt * 16 + r16;
    const float* U = Ug[n >> 8];
    const int c = n & 255;
#pragma unroll
    for (int kk = 0; kk < 8; ++kk) {
      const int kb = kk * 32 + kgrp * 8;
      bf16x8 v;
#pragma unroll
      for (int e = 0; e < 8; ++e) v[e] = (__bf16)U[(size_t)(kb + e) * HID + c];
      b[nt][kk] = v;
    }
  }

  for (int mi = 0; mi < 4; ++mi) {
    const int tok = tokp[m0 + mi * 16 + r16];
    const float* x = embp + (size_t)tok * DIM;
    bf16x8 a[8];
#pragma unroll
    for (int kk = 0; kk < 8; ++kk) {
      const int kb = kk * 32 + kgrp * 8;
      const float4 u0 = *reinterpret_cast<const float4*>(x + kb);
      const float4 u1 = *reinterpret_cast<const float4*>(x + kb + 4);
      bf16x8 v;
      v[0] = (__bf16)u0.x; v[1] = (__bf16)u0.y; v[2] = (__bf16)u0.z; v[3] = (__bf16)u0.w;
      v[4] = (__bf16)u1.x; v[5] = (__bf16)u1.y; v[6] = (__bf16)u1.z; v[7] = (__bf16)u1.w;
      a[kk] = v;
    }
#pragma unroll
    for (int nt = 0; nt < 4; ++nt) {
      f32x4 acc = {0.f, 0.f, 0.f, 0.f};
#pragma unroll
      for (int kk = 0; kk < 8; ++kk)
        acc = __builtin_amdgcn_mfma_f32_16x16x32_bf16(a[kk], b[nt][kk], acc, 0, 0, 0);
      const int n = n0 + nt * 16 + r16;
#pragma unroll
      for (int r = 0; r < 4; ++r)
        XU[(size_t)(m0 + mi * 16 + kgrp * 4 + r) * 1024 + n] = acc[r];
    }
  }
}

// ---------------- persistent LSTM: 6 WGs, relaxed-agent atomics only ----------------
// bx 0,1: layer 0 (a=bx), 4 gates x cols [128a,128a+128), K=256 (XU precomputed).
// bx 2..5: layer 1 (b=bx-2), 4 gates x cols [64b,64b+64), K=512 ([h1(t-1); h0(t)]).
// flags flg[t*8 + w]: w=0,1 -> L0 WGs; w=4..7 -> L1 WGs. Advisory (sentinel backstop).
__global__ __launch_bounds__(512, 2) void lstm_kernel(
    const float* __restrict__ wF, const float* __restrict__ bF,
    const float* __restrict__ wI, const float* __restrict__ bI,
    const float* __restrict__ wC, const float* __restrict__ bC,
    const float* __restrict__ wO, const float* __restrict__ bO,
    const float* __restrict__ uF, const float* __restrict__ uI,
    const float* __restrict__ uC, const float* __restrict__ uO,
    const float* __restrict__ XU, u32* __restrict__ h0w, u32* __restrict__ h1w,
    u32* __restrict__ flg, float* __restrict__ dout)
{
  const int tid  = threadIdx.x;
  const int lane = tid & 63;
  const int wv   = tid >> 6;
  const int bx   = blockIdx.x;
  const int gate = wv >> 1;
  const int hf   = wv & 1;
  const int r16  = lane & 15;
  const int kgrp = lane >> 4;

  const float* Wg[4] = {wF, wI, wC, wO};
  const float* Ug[4] = {uF, uI, uC, uO};
  const float* Bg[4] = {bF, bI, bC, bO};

  __shared__ float gbuf[4][16][132];
  const size_t logitsN = (size_t)SEQ * BATCH * NVOC;
  const int eb = tid >> 5;

  if (bx < 2) {
    // ================= layer 0 =================
    const int a = bx;
    bf16x8 bw[4][8];
    float bias[4];
    int xucol[4];
#pragma unroll
    for (int nt = 0; nt < 4; ++nt) {
      const int n = a * 128 + hf * 64 + nt * 16 + r16;
      bias[nt] = Bg[gate][n];
      xucol[nt] = gate * 256 + n;
#pragma unroll
      for (int kk = 0; kk < 8; ++kk) {
        const int kb = kk * 32 + kgrp * 8;
        bf16x8 v;
#pragma unroll
        for (int e = 0; e < 8; ++e) v[e] = (__bf16)Wg[gate][(size_t)(kb + e) * HID + n];
        bw[nt][kk] = v;
      }
    }
    float cst[4] = {0.f, 0.f, 0.f, 0.f};

    for (int t = 0; t < SEQ; ++t) {
      if (t > 0) {
        if (tid == 0) {
          int g = 0;
          while (AL32(&flg[(t - 1) * 8 + (1 - a)]) == 0u && ++g < GUARD) {}
        }
        __syncthreads();
      }

      f32x4 acc[4];
#pragma unroll
      for (int nt = 0; nt < 4; ++nt) { acc[nt][0]=0.f; acc[nt][1]=0.f; acc[nt][2]=0.f; acc[nt][3]=0.f; }

      if (t > 0) {
        const u32* hr = h0w + ((size_t)(t - 1) * BATCH + r16) * 128 + kgrp * 4;
        u64 w[8][2];
        int guard = 0;
        bool ok;
        do {
          ok = true;
#pragma unroll
          for (int kk = 0; kk < 8; ++kk) {
            w[kk][0] = AL64(hr + kk * 16);
            w[kk][1] = AL64(hr + kk * 16 + 2);
            ok = ok && ((u32)w[kk][0] != SENT) && ((u32)(w[kk][0] >> 32) != SENT)
                    && ((u32)w[kk][1] != SENT) && ((u32)(w[kk][1] >> 32) != SENT);
          }
        } while (!__all(ok) && ++guard < GUARD);
#pragma unroll
        for (int kk = 0; kk < 8; ++kk) {
          u32x4v v;
          v[0] = (u32)w[kk][0]; v[1] = (u32)(w[kk][0] >> 32);
          v[2] = (u32)w[kk][1]; v[3] = (u32)(w[kk][1] >> 32);
          const bf16x8 aa = __builtin_bit_cast(bf16x8, v);
#pragma unroll
          for (int nt = 0; nt < 4; ++nt)
            acc[nt] = __builtin_amdgcn_mfma_f32_16x16x32_bf16(aa, bw[nt][kk], acc[nt], 0, 0, 0);
        }
      }

      const float* xp = XU + (size_t)t * BATCH * 1024;
#pragma unroll
      for (int nt = 0; nt < 4; ++nt) {
        const int c = hf * 64 + nt * 16 + r16;
#pragma unroll
        for (int r = 0; r < 4; ++r) {
          const float z = acc[nt][r] + bias[nt] + xp[(size_t)(kgrp * 4 + r) * 1024 + xucol[nt]];
          gbuf[gate][kgrp * 4 + r][c] = (gate == 2) ? tanhf(z) : 1.f / (1.f + expf(-z));
        }
      }
      __syncthreads();

      // c/h update: 4 cols/thread within [0,128)
      const int ec = (tid & 31) * 4;
      float hv[4];
#pragma unroll
      for (int j = 0; j < 4; ++j) {
        const float ff = gbuf[0][eb][ec + j];
        const float ii = gbuf[1][eb][ec + j];
        const float gg = gbuf[2][eb][ec + j];
        const float oo = gbuf[3][eb][ec + j];
        cst[j] = ff * cst[j] + ii * gg;
        hv[j] = oo * tanhf(cst[j]);
      }
      const u32 lo = (u32)__builtin_bit_cast(u16, (__bf16)hv[0]) |
                     ((u32)__builtin_bit_cast(u16, (__bf16)hv[1]) << 16);
      const u32 hi = (u32)__builtin_bit_cast(u16, (__bf16)hv[2]) |
                     ((u32)__builtin_bit_cast(u16, (__bf16)hv[3]) << 16);
      AS64(h0w + ((size_t)t * BATCH + eb) * 128 + a * 64 + ec / 2,
           (u64)lo | ((u64)hi << 32));

      if (t == SEQ - 1) {
        const int n = a * 128 + ec;
        float* hT = dout + logitsN + (size_t)eb * HID + n;
        float* cT = dout + logitsN + (size_t)NLAYER * BATCH * HID + (size_t)eb * HID + n;
#pragma unroll
        for (int j = 0; j < 4; ++j) { hT[j] = hv[j]; cT[j] = cst[j]; }
      }
      __syncthreads();            // all threads' h stores complete (vmcnt drained)
      if (tid == 0) AS32(&flg[t * 8 + a], 1u);
    }
  } else {
    // ================= layer 1 =================
    const int b = bx - 2;
    bf16x8 bw[2][16];
    float bias[2];
#pragma unroll
    for (int nt = 0; nt < 2; ++nt) {
      const int n = b * 64 + hf * 32 + nt * 16 + r16;
      bias[nt] = Bg[gate][n];
#pragma unroll
      for (int kk = 0; kk < 8; ++kk) {
        const int kb = kk * 32 + kgrp * 8;
        bf16x8 v, u;
#pragma unroll
        for (int e = 0; e < 8; ++e) {
          v[e] = (__bf16)Wg[gate][(size_t)(kb + e) * HID + n];
          u[e] = (__bf16)Ug[gate][(size_t)(kb + e) * HID + n];
        }
        bw[nt][kk] = v;       // h1(t-1) part
        bw[nt][kk + 8] = u;   // h0(t) part
      }
    }
    float c0 = 0.f, c1 = 0.f;

    for (int t = 0; t < SEQ; ++t) {
      if (tid == 0) {
        int g = 0;
        for (;;) {
          const u64 fa = AL64(flg + t * 8);
          bool ok = ((u32)fa != 0u) && ((u32)(fa >> 32) != 0u);
          if (t > 0) {
            const u64 fb0 = AL64(flg + (t - 1) * 8 + 4);
            const u64 fb1 = AL64(flg + (t - 1) * 8 + 6);
            ok = ok && ((u32)fb0 != 0u) && ((u32)(fb0 >> 32) != 0u)
                    && ((u32)fb1 != 0u) && ((u32)(fb1 >> 32) != 0u);
          }
          if (ok || ++g >= GUARD) break;
        }
      }
      __syncthreads();

      u64 w1[8][2], w0[8][2];
      {
        const u32* xr = h0w + ((size_t)t * BATCH + r16) * 128 + kgrp * 4;
        const u32* hr = h1w + ((size_t)(t - 1) * BATCH + r16) * 128 + kgrp * 4;
        int guard = 0;
        bool ok;
        do {
          ok = true;
#pragma unroll
          for (int kk = 0; kk < 8; ++kk) {
            w0[kk][0] = AL64(xr + kk * 16);
            w0[kk][1] = AL64(xr + kk * 16 + 2);
            ok = ok && ((u32)w0[kk][0] != SENT) && ((u32)(w0[kk][0] >> 32) != SENT)
                    && ((u32)w0[kk][1] != SENT) && ((u32)(w0[kk][1] >> 32) != SENT);
          }
          if (t > 0) {
#pragma unroll
            for (int kk = 0; kk < 8; ++kk) {
              w1[kk][0] = AL64(hr + kk * 16);
              w1[kk][1] = AL64(hr + kk * 16 + 2);
              ok = ok && ((u32)w1[kk][0] != SENT) && ((u32)(w1[kk][0] >> 32) != SENT)
                      && ((u32)w1[kk][1] != SENT) && ((u32)(w1[kk][1] >> 32) != SENT);
            }
          }
        } while (!__all(ok) && ++guard < GUARD);
      }

      f32x4 acc[2];
#pragma unroll
      for (int nt = 0; nt < 2; ++nt) { acc[nt][0]=0.f; acc[nt][1]=0.f; acc[nt][2]=0.f; acc[nt][3]=0.f; }

      if (t > 0) {
#pragma unroll
        for (int kk = 0; kk < 8; ++kk) {
          u32x4v v;
          v[0] = (u32)w1[kk][0]; v[1] = (u32)(w1[kk][0] >> 32);
          v[2] = (u32)w1[kk][1]; v[3] = (u32)(w1[kk][1] >> 32);
          const bf16x8 aa = __builtin_bit_cast(bf16x8, v);
          acc[0] = __builtin_amdgcn_mfma_f32_16x16x32_bf16(aa, bw[0][kk], acc[0], 0, 0, 0);
          acc[1] = __builtin_amdgcn_mfma_f32_16x16x32_bf16(aa, bw[1][kk], acc[1], 0, 0, 0);
        }
      }
#pragma unroll
      for (int kk = 0; kk < 8; ++kk) {
        u32x4v v;
        v[0] = (u32)w0[kk][0]; v[1] = (u32)(w0[kk][0] >> 32);
        v[2] = (u32)w0[kk][1]; v[3] = (u32)(w0[kk][1] >> 32);
        const bf16x8 aa = __builtin_bit_cast(bf16x8, v);
        acc[0] = __builtin_amdgcn_mfma_f32_16x16x32_bf16(aa, bw[0][kk + 8], acc[0], 0, 0, 0);
        acc[1] = __builtin_amdgcn_mfma_f32_16x16x32_bf16(aa, bw[1][kk + 8], acc[1], 0, 0, 0);
      }

#pragma unroll
      for (int nt = 0; nt < 2; ++nt) {
        const int c = hf * 32 + nt * 16 + r16;
#pragma unroll
        for (int r = 0; r < 4; ++r) {
          const float z = acc[nt][r] + bias[nt];
          gbuf[gate][kgrp * 4 + r][c] = (gate == 2) ? tanhf(z) : 1.f / (1.f + expf(-z));
        }
      }
      __syncthreads();

      // c/h update: 2 cols/thread within [0,64)
      const int ec = (tid & 31) * 2;
      const float ff0 = gbuf[0][eb][ec], ff1 = gbuf[0][eb][ec + 1];
      const float ii0 = gbuf[1][eb][ec], ii1 = gbuf[1][eb][ec + 1];
      const float gg0 = gbuf[2][eb][ec], gg1 = gbuf[2][eb][ec + 1];
      const float oo0 = gbuf[3][eb][ec], oo1 = gbuf[3][eb][ec + 1];
      c0 = ff0 * c0 + ii0 * gg0;
      c1 = ff1 * c1 + ii1 * gg1;
      const float hv0 = oo0 * tanhf(c0);
      const float hv1 = oo1 * tanhf(c1);
      const u32 pk = (u32)__builtin_bit_cast(u16, (__bf16)hv0) |
                     ((u32)__builtin_bit_cast(u16, (__bf16)hv1) << 16);
      AS32(h1w + ((size_t)t * BATCH + eb) * 128 + b * 32 + ec / 2, pk);

      if (t == SEQ - 1) {
        const int n = b * 64 + ec;
        float* hT = dout + logitsN + (size_t)(BATCH + eb) * HID + n;
        float* cT = dout + logitsN + (size_t)NLAYER * BATCH * HID + (size_t)(BATCH + eb) * HID + n;
        hT[0] = hv0; hT[1] = hv1;
        cT[0] = c0;  cT[1] = c1;
      }
      __syncthreads();            // all threads' h stores complete
      if (tid == 0) AS32(&flg[t * 8 + 4 + b], 1u);
    }
  }
}

// ---------------- decoder: dec_w read once; loop M inside ----------------
// grid (2, 393): M-half x 128-vocab-row chunk. 256 thr; wave wv owns 32 vocab rows.
__global__ __launch_bounds__(256) void dec_kernel(
    const u16* __restrict__ htb, const u16* __restrict__ dwb,
    const float* __restrict__ dbp, float* __restrict__ out)
{
  const int tid  = threadIdx.x;
  const int lane = tid & 63;
  const int wv   = tid >> 6;
  const int r16  = lane & 15;
  const int kgrp = lane >> 4;
  const int mh   = blockIdx.x;
  const int n0   = blockIdx.y * 128 + wv * 32;

  bf16x8 b[2][8];
  float bb[2];
#pragma unroll
  for (int nt = 0; nt < 2; ++nt) {
    const int v = n0 + nt * 16 + r16;
    const int vc = (v < NVOC) ? v : (NVOC - 1);
    bb[nt] = dbp[vc];
    const u16* bp = dwb + (size_t)vc * HID + kgrp * 8;
#pragma unroll
    for (int kk = 0; kk < 8; ++kk)
      b[nt][kk] = *reinterpret_cast<const bf16x8*>(bp + kk * 32);
  }

  for (int mi = 0; mi < 64; ++mi) {
    const int m = mh * 1024 + mi * 16;
    const u16* ap = htb + ((size_t)(m + r16)) * HID + kgrp * 8;
    bf16x8 a[8];
#pragma unroll
    for (int kk = 0; kk < 8; ++kk)
      a[kk] = *reinterpret_cast<const bf16x8*>(ap + kk * 32);

    f32x4 acc[2];
#pragma unroll
    for (int nt = 0; nt < 2; ++nt) { acc[nt][0]=0.f; acc[nt][1]=0.f; acc[nt][2]=0.f; acc[nt][3]=0.f; }
#pragma unroll
    for (int kk = 0; kk < 8; ++kk) {
      acc[0] = __builtin_amdgcn_mfma_f32_16x16x32_bf16(a[kk], b[0][kk], acc[0], 0, 0, 0);
      acc[1] = __builtin_amdgcn_mfma_f32_16x16x32_bf16(a[kk], b[1][kk], acc[1], 0, 0, 0);
    }
#pragma unroll
    for (int nt = 0; nt < 2; ++nt) {
      const int v = n0 + nt * 16 + r16;
      if (v < NVOC) {
#pragma unroll
        for (int r = 0; r < 4; ++r)
          out[(size_t)(m + kgrp * 4 + r) * NVOC + v] = acc[nt][r] + bb[nt];
      }
    }
  }
}

extern "C" void kernel_launch(void* const* d_in, const int* in_sizes, int n_in,
                              void* d_out, int out_size, void* d_ws, size_t ws_size,
                              hipStream_t stream) {
  const int*   tokp = (const int*)d_in[0];
  const float* embp = (const float*)d_in[1];
  const float* wF = (const float*)d_in[2];
  const float* uF = (const float*)d_in[3];
  const float* bF = (const float*)d_in[4];
  const float* wI = (const float*)d_in[5];
  const float* uI = (const float*)d_in[6];
  const float* bI = (const float*)d_in[7];
  const float* wC = (const float*)d_in[8];
  const float* uC = (const float*)d_in[9];
  const float* bC = (const float*)d_in[10];
  const float* wO = (const float*)d_in[11];
  const float* uO = (const float*)d_in[12];
  const float* bO = (const float*)d_in[13];
  const float* dw = (const float*)d_in[14];
  const float* db = (const float*)d_in[15];
  float* out = (float*)d_out;

  char* ws = (char*)d_ws;
  size_t off = 0;
  char* regionA = ws;                           // XU (8 MB) aliased with dwb (25.7 MB)
  off += (size_t)NVOC * HID * 2;
  off = (off + 255) & ~(size_t)255;
  u32* h0w = (u32*)(ws + off); off += (size_t)SEQ * BATCH * HID * 2;  // h0w + h1w contiguous
  u32* h1w = (u32*)(ws + off); off += (size_t)SEQ * BATCH * HID * 2;
  u32* flg = (u32*)(ws + off); off += (size_t)SEQ * 8 * 4;

  float* XU  = (float*)regionA;
  u16*   dwb = (u16*)regionA;

  // xu (writes XU, sentinel-fills h0w/h1w, zeroes flg) -> lstm ->
  // prep (overwrites region A with dwb) -> dec (reads dwb, h1w)
  xu_kernel<<<dim3(32, 4), 256, 0, stream>>>(tokp, embp, uF, uI, uC, uO, XU, h0w, flg);
  lstm_kernel<<<6, 512, 0, stream>>>(wF, bF, wI, bI, wC, bC, wO, bO,
                                     uF, uI, uC, uO, XU, h0w, h1w, flg, out);
  prep_kernel<<<1024, 256, 0, stream>>>(dw, dwb, NVOC * HID / 4);
  dec_kernel<<<dim3(2, (NVOC + 127) / 128), 256, 0, stream>>>((const u16*)h1w, dwb, db, out);
}

// Round 6
// 1570.761 us; speedup vs baseline: 1.6855x; 1.0060x over previous
//
#include <hip/hip_runtime.h>
#include <hip/hip_bf16.h>

#define NVOC 50257
#define DIM 256
#define HID 256
#define NLAYER 2
#define SEQ 128
#define BATCH 16
#define GUARD (1 << 20)

typedef __bf16 bf16x8 __attribute__((ext_vector_type(8)));
typedef float f32x4 __attribute__((ext_vector_type(4)));
typedef unsigned short u16;
typedef unsigned int u32;
typedef unsigned long long u64;

#define AL64(p)   __hip_atomic_load((const u64*)(p), __ATOMIC_RELAXED, __HIP_MEMORY_SCOPE_AGENT)
#define AS32(p,v) __hip_atomic_store((u32*)(p), (v), __ATOMIC_RELAXED, __HIP_MEMORY_SCOPE_AGENT)

__device__ __forceinline__ float fsig(float z) { return 1.f / (1.f + __expf(-z)); }
__device__ __forceinline__ float ftanh(float z) {
  const float x = fminf(fmaxf(z, -15.f), 15.f);
  const float e = __expf(2.f * x);
  return (e - 1.f) / (e + 1.f);
}
__device__ __forceinline__ bf16x8 cvt8(const float4 u0, const float4 u1) {
  bf16x8 v;
  v[0] = (__bf16)u0.x; v[1] = (__bf16)u0.y; v[2] = (__bf16)u0.z; v[3] = (__bf16)u0.w;
  v[4] = (__bf16)u1.x; v[5] = (__bf16)u1.y; v[6] = (__bf16)u1.z; v[7] = (__bf16)u1.w;
  return v;
}

// ---------------- prep: dec_w f32 -> bf16 ----------------
__global__ void prep_kernel(const float* __restrict__ dw, u16* __restrict__ dwb, int n4) {
  int tid = blockIdx.x * blockDim.x + threadIdx.x;
  int stride = gridDim.x * blockDim.x;
  for (int i = tid; i < n4; i += stride) {
    float4 v = reinterpret_cast<const float4*>(dw)[i];
    ushort4 o;
    o.x = __builtin_bit_cast(u16, (__bf16)v.x);
    o.y = __builtin_bit_cast(u16, (__bf16)v.y);
    o.z = __builtin_bit_cast(u16, (__bf16)v.z);
    o.w = __builtin_bit_cast(u16, (__bf16)v.w);
    reinterpret_cast<ushort4*>(dwb)[i] = o;
  }
}

// ---------------- XU precompute + atomic flag zero ----------------
// XU[t*16+b][g*256+c] = emb[tok[t,b]] @ U_g. Grid (32,4) x 256.
__global__ __launch_bounds__(256) void xu_kernel(
    const int* __restrict__ tokp, const float* __restrict__ embp,
    const float* __restrict__ uF, const float* __restrict__ uI,
    const float* __restrict__ uC, const float* __restrict__ uO,
    float* __restrict__ XU, u32* __restrict__ flg)
{
  const int tid = threadIdx.x;
  if (blockIdx.x == 0 && blockIdx.y == 0)
    for (int i = tid; i < SEQ * 8; i += 256) AS32(&flg[i], 0u);   // write-through zero

  const int lane = tid & 63, wv = tid >> 6, r16 = lane & 15, kgrp = lane >> 4;
  const int m0 = blockIdx.x * 64;
  const int n0 = blockIdx.y * 256 + wv * 64;
  const float* Ug[4] = {uF, uI, uC, uO};

  bf16x8 b[4][8];
#pragma unroll
  for (int nt = 0; nt < 4; ++nt) {
    const int n = n0 + nt * 16 + r16;
    const float* U = Ug[n >> 8];
    const int c = n & 255;
#pragma unroll
    for (int kk = 0; kk < 8; ++kk) {
      const int kb = kk * 32 + kgrp * 8;
      bf16x8 v;
#pragma unroll
      for (int e = 0; e < 8; ++e) v[e] = (__bf16)U[(size_t)(kb + e) * HID + c];
      b[nt][kk] = v;
    }
  }

  for (int mi = 0; mi < 4; ++mi) {
    const int tok = tokp[m0 + mi * 16 + r16];
    const float* x = embp + (size_t)tok * DIM;
    bf16x8 a[8];
#pragma unroll
    for (int kk = 0; kk < 8; ++kk) {
      const int kb = kk * 32 + kgrp * 8;
      a[kk] = cvt8(*reinterpret_cast<const float4*>(x + kb),
                   *reinterpret_cast<const float4*>(x + kb + 4));
    }
#pragma unroll
    for (int nt = 0; nt < 4; ++nt) {
      f32x4 acc = {0.f, 0.f, 0.f, 0.f};
#pragma unroll
      for (int kk = 0; kk < 8; ++kk)
        acc = __builtin_amdgcn_mfma_f32_16x16x32_bf16(a[kk], b[nt][kk], acc, 0, 0, 0);
      const int n = n0 + nt * 16 + r16;
#pragma unroll
      for (int r = 0; r < 4; ++r)
        XU[(size_t)(m0 + mi * 16 + kgrp * 4 + r) * 1024 + n] = acc[r];
    }
  }
}

// ---------------- persistent LSTM: 8 WGs x 256 thr, all-gates-per-wave ----------------
// bx 0..3: layer 0 quarter q=bx   (cols [64q,64q+64)), K=256 (XU precomputed).
// bx 4..7: layer 1 quarter q=bx-4 (cols [64q,64q+64)), K=512 ([h1(t-1); h0(t)]).
// Wave wv owns cols [64q+16wv, +16) x ALL 4 gates -> c/h update fully in-register.
// h stored f32 via write-through atomic u32 stores; consumers use PLAIN float4
// loads gated by narrow atomic flag polls (R2-proven recipe). No LDS, no fences.
__global__ __launch_bounds__(256, 1) void lstm_kernel(
    const float* __restrict__ wF, const float* __restrict__ bF,
    const float* __restrict__ wI, const float* __restrict__ bI,
    const float* __restrict__ wC, const float* __restrict__ bC,
    const float* __restrict__ wO, const float* __restrict__ bO,
    const float* __restrict__ uF, const float* __restrict__ uI,
    const float* __restrict__ uC, const float* __restrict__ uO,
    const float* __restrict__ XU, u32* __restrict__ h0w, u32* __restrict__ h1w,
    u32* __restrict__ flg, float* __restrict__ dout)
{
  const int tid  = threadIdx.x;
  const int lane = tid & 63;
  const int wv   = tid >> 6;         // 0..3
  const int r16  = lane & 15;
  const int kgrp = lane >> 4;
  const int bx   = blockIdx.x;       // 0..7
  const int l    = bx >> 2;
  const int q    = bx & 3;
  const int col  = q * 64 + wv * 16 + r16;

  const float* Wg[4] = {wF, wI, wC, wO};
  const float* Ug[4] = {uF, uI, uC, uO};
  const float* Bg[4] = {bF, bI, bC, bO};
  const float* h0f = (const float*)h0w;
  const float* h1f = (const float*)h1w;
  const size_t logitsN = (size_t)SEQ * BATCH * NVOC;

  float bias[4];
#pragma unroll
  for (int g = 0; g < 4; ++g) bias[g] = Bg[g][col];
  float cst[4] = {0.f, 0.f, 0.f, 0.f};

  if (l == 0) {
    // ================= layer 0 (K=256: W only; x@U is XU) =================
    bf16x8 bw[4][8];
#pragma unroll
    for (int g = 0; g < 4; ++g)
#pragma unroll
      for (int kk = 0; kk < 8; ++kk) {
        const int kb = kk * 32 + kgrp * 8;
        bf16x8 v;
#pragma unroll
        for (int e = 0; e < 8; ++e) v[e] = (__bf16)Wg[g][(size_t)(kb + e) * HID + col];
        bw[g][kk] = v;
      }

    for (int t = 0; t < SEQ; ++t) {
      if (t > 0) {
        int gd = 0;
        for (;;) {
          const u64 f0 = AL64(flg + (size_t)(t - 1) * 8);
          const u64 f1 = AL64(flg + (size_t)(t - 1) * 8 + 2);
          if (((u32)f0 & (u32)(f0 >> 32) & (u32)f1 & (u32)(f1 >> 32)) != 0u) break;
          if (++gd >= GUARD) break;
        }
        asm volatile("" ::: "memory");   // keep data loads below the poll
      }

      f32x4 acc[4];
#pragma unroll
      for (int g = 0; g < 4; ++g) { acc[g][0]=0.f; acc[g][1]=0.f; acc[g][2]=0.f; acc[g][3]=0.f; }

      if (t > 0) {
        const float* hr = h0f + ((size_t)(t - 1) * BATCH + r16) * HID + kgrp * 8;
#pragma unroll
        for (int kk = 0; kk < 8; ++kk) {
          const bf16x8 a = cvt8(*reinterpret_cast<const float4*>(hr + kk * 32),
                                *reinterpret_cast<const float4*>(hr + kk * 32 + 4));
#pragma unroll
          for (int g = 0; g < 4; ++g)
            acc[g] = __builtin_amdgcn_mfma_f32_16x16x32_bf16(a, bw[g][kk], acc[g], 0, 0, 0);
        }
      }

      const float* xp = XU + (size_t)t * BATCH * 1024 + col;
      float hv[4];
#pragma unroll
      for (int r = 0; r < 4; ++r) {
        const int b = kgrp * 4 + r;
        const float zf = acc[0][r] + bias[0] + xp[(size_t)b * 1024];
        const float zi = acc[1][r] + bias[1] + xp[(size_t)b * 1024 + 256];
        const float zg = acc[2][r] + bias[2] + xp[(size_t)b * 1024 + 512];
        const float zo = acc[3][r] + bias[3] + xp[(size_t)b * 1024 + 768];
        const float f = fsig(zf), i = fsig(zi), g = ftanh(zg), o = fsig(zo);
        cst[r] = f * cst[r] + i * g;
        hv[r] = o * ftanh(cst[r]);
        AS32(h0w + ((size_t)t * BATCH + b) * HID + col, __builtin_bit_cast(u32, hv[r]));
      }

      if (t == SEQ - 1) {
#pragma unroll
        for (int r = 0; r < 4; ++r) {
          const int b = kgrp * 4 + r;
          dout[logitsN + (size_t)b * HID + col] = hv[r];
          dout[logitsN + (size_t)NLAYER * BATCH * HID + (size_t)b * HID + col] = cst[r];
        }
      }
      __syncthreads();                 // drains vmcnt(0): all waves' h stores done
      if (tid == 0) AS32(&flg[(size_t)t * 8 + q], 1u);
    }
  } else {
    // ================= layer 1 (K=512: [h1(t-1); h0(t)]) =================
    bf16x8 bw[4][16];
#pragma unroll
    for (int g = 0; g < 4; ++g)
#pragma unroll
      for (int kk = 0; kk < 8; ++kk) {
        const int kb = kk * 32 + kgrp * 8;
        bf16x8 v, u;
#pragma unroll
        for (int e = 0; e < 8; ++e) {
          v[e] = (__bf16)Wg[g][(size_t)(kb + e) * HID + col];
          u[e] = (__bf16)Ug[g][(size_t)(kb + e) * HID + col];
        }
        bw[g][kk] = v;        // h1(t-1) part
        bw[g][kk + 8] = u;    // h0(t) part
      }

    for (int t = 0; t < SEQ; ++t) {
      {
        int gd = 0;
        for (;;) {
          const u64 f0 = AL64(flg + (size_t)t * 8);        // L0 flags 0,1 @ t
          const u64 f1 = AL64(flg + (size_t)t * 8 + 2);    // L0 flags 2,3 @ t
          u32 ok = (u32)f0 & (u32)(f0 >> 32) & (u32)f1 & (u32)(f1 >> 32);
          if (t > 0) {
            const u64 g0 = AL64(flg + (size_t)(t - 1) * 8 + 4);
            const u64 g1 = AL64(flg + (size_t)(t - 1) * 8 + 6);
            ok &= (u32)g0 & (u32)(g0 >> 32) & (u32)g1 & (u32)(g1 >> 32);
          }
          if (ok) break;
          if (++gd >= GUARD) break;
        }
        asm volatile("" ::: "memory");
      }

      f32x4 acc[4];
#pragma unroll
      for (int g = 0; g < 4; ++g) { acc[g][0]=0.f; acc[g][1]=0.f; acc[g][2]=0.f; acc[g][3]=0.f; }

      if (t > 0) {
        const float* hr = h1f + ((size_t)(t - 1) * BATCH + r16) * HID + kgrp * 8;
#pragma unroll
        for (int kk = 0; kk < 8; ++kk) {
          const bf16x8 a = cvt8(*reinterpret_cast<const float4*>(hr + kk * 32),
                                *reinterpret_cast<const float4*>(hr + kk * 32 + 4));
#pragma unroll
          for (int g = 0; g < 4; ++g)
            acc[g] = __builtin_amdgcn_mfma_f32_16x16x32_bf16(a, bw[g][kk], acc[g], 0, 0, 0);
        }
      }
      {
        const float* xr = h0f + ((size_t)t * BATCH + r16) * HID + kgrp * 8;
#pragma unroll
        for (int kk = 0; kk < 8; ++kk) {
          const bf16x8 a = cvt8(*reinterpret_cast<const float4*>(xr + kk * 32),
                                *reinterpret_cast<const float4*>(xr + kk * 32 + 4));
#pragma unroll
          for (int g = 0; g < 4; ++g)
            acc[g] = __builtin_amdgcn_mfma_f32_16x16x32_bf16(a, bw[g][kk + 8], acc[g], 0, 0, 0);
        }
      }

      float hv[4];
#pragma unroll
      for (int r = 0; r < 4; ++r) {
        const int b = kgrp * 4 + r;
        const float zf = acc[0][r] + bias[0];
        const float zi = acc[1][r] + bias[1];
        const float zg = acc[2][r] + bias[2];
        const float zo = acc[3][r] + bias[3];
        const float f = fsig(zf), i = fsig(zi), g = ftanh(zg), o = fsig(zo);
        cst[r] = f * cst[r] + i * g;
        hv[r] = o * ftanh(cst[r]);
        AS32(h1w + ((size_t)t * BATCH + b) * HID + col, __builtin_bit_cast(u32, hv[r]));
      }

      if (t == SEQ - 1) {
#pragma unroll
        for (int r = 0; r < 4; ++r) {
          const int b = kgrp * 4 + r;
          dout[logitsN + (size_t)(BATCH + b) * HID + col] = hv[r];
          dout[logitsN + (size_t)NLAYER * BATCH * HID + (size_t)(BATCH + b) * HID + col] = cst[r];
        }
      }
      __syncthreads();
      if (tid == 0) AS32(&flg[(size_t)t * 8 + 4 + q], 1u);
    }
  }
}

// ---------------- decoder: dec_w read once; loop M inside; h1 is f32 ----------------
// grid (2, 393): M-half x 128-vocab-row chunk. 256 thr; wave wv owns 32 vocab rows.
__global__ __launch_bounds__(256) void dec_kernel(
    const float* __restrict__ htf, const u16* __restrict__ dwb,
    const float* __restrict__ dbp, float* __restrict__ out)
{
  const int tid  = threadIdx.x;
  const int lane = tid & 63;
  const int wv   = tid >> 6;
  const int r16  = lane & 15;
  const int kgrp = lane >> 4;
  const int mh   = blockIdx.x;
  const int n0   = blockIdx.y * 128 + wv * 32;

  bf16x8 b[2][8];
  float bb[2];
#pragma unroll
  for (int nt = 0; nt < 2; ++nt) {
    const int v = n0 + nt * 16 + r16;
    const int vc = (v < NVOC) ? v : (NVOC - 1);
    bb[nt] = dbp[vc];
    const u16* bp = dwb + (size_t)vc * HID + kgrp * 8;
#pragma unroll
    for (int kk = 0; kk < 8; ++kk)
      b[nt][kk] = *reinterpret_cast<const bf16x8*>(bp + kk * 32);
  }

  for (int mi = 0; mi < 64; ++mi) {
    const int m = mh * 1024 + mi * 16;
    const float* ap = htf + (size_t)(m + r16) * HID + kgrp * 8;
    bf16x8 a[8];
#pragma unroll
    for (int kk = 0; kk < 8; ++kk)
      a[kk] = cvt8(*reinterpret_cast<const float4*>(ap + kk * 32),
                   *reinterpret_cast<const float4*>(ap + kk * 32 + 4));

    f32x4 acc[2];
#pragma unroll
    for (int nt = 0; nt < 2; ++nt) { acc[nt][0]=0.f; acc[nt][1]=0.f; acc[nt][2]=0.f; acc[nt][3]=0.f; }
#pragma unroll
    for (int kk = 0; kk < 8; ++kk) {
      acc[0] = __builtin_amdgcn_mfma_f32_16x16x32_bf16(a[kk], b[0][kk], acc[0], 0, 0, 0);
      acc[1] = __builtin_amdgcn_mfma_f32_16x16x32_bf16(a[kk], b[1][kk], acc[1], 0, 0, 0);
    }
#pragma unroll
    for (int nt = 0; nt < 2; ++nt) {
      const int v = n0 + nt * 16 + r16;
      if (v < NVOC) {
#pragma unroll
        for (int r = 0; r < 4; ++r)
          out[(size_t)(m + kgrp * 4 + r) * NVOC + v] = acc[nt][r] + bb[nt];
      }
    }
  }
}

extern "C" void kernel_launch(void* const* d_in, const int* in_sizes, int n_in,
                              void* d_out, int out_size, void* d_ws, size_t ws_size,
                              hipStream_t stream) {
  const int*   tokp = (const int*)d_in[0];
  const float* embp = (const float*)d_in[1];
  const float* wF = (const float*)d_in[2];
  const float* uF = (const float*)d_in[3];
  const float* bF = (const float*)d_in[4];
  const float* wI = (const float*)d_in[5];
  const float* uI = (const float*)d_in[6];
  const float* bI = (const float*)d_in[7];
  const float* wC = (const float*)d_in[8];
  const float* uC = (const float*)d_in[9];
  const float* bC = (const float*)d_in[10];
  const float* wO = (const float*)d_in[11];
  const float* uO = (const float*)d_in[12];
  const float* bO = (const float*)d_in[13];
  const float* dw = (const float*)d_in[14];
  const float* db = (const float*)d_in[15];
  float* out = (float*)d_out;

  char* ws = (char*)d_ws;
  size_t off = 0;
  char* regionA = ws;                           // XU (8 MB) aliased with dwb (25.7 MB)
  off += (size_t)NVOC * HID * 2;
  off = (off + 255) & ~(size_t)255;
  u32* h0w = (u32*)(ws + off); off += (size_t)SEQ * BATCH * HID * 4;   // f32 h0
  u32* h1w = (u32*)(ws + off); off += (size_t)SEQ * BATCH * HID * 4;   // f32 h1
  u32* flg = (u32*)(ws + off); off += (size_t)SEQ * 8 * 4;

  float* XU  = (float*)regionA;
  u16*   dwb = (u16*)regionA;

  // xu (writes XU, atomically zeroes flg) -> lstm ->
  // prep (overwrites region A with dwb) -> dec (reads dwb, h1w)
  xu_kernel<<<dim3(32, 4), 256, 0, stream>>>(tokp, embp, uF, uI, uC, uO, XU, flg);
  lstm_kernel<<<8, 256, 0, stream>>>(wF, bF, wI, bI, wC, bC, wO, bO,
                                     uF, uI, uC, uO, XU, h0w, h1w, flg, out);
  prep_kernel<<<1024, 256, 0, stream>>>(dw, dwb, NVOC * HID / 4);
  dec_kernel<<<dim3(2, (NVOC + 127) / 128), 256, 0, stream>>>((const float*)h1w, dwb, db, out);
}

// Round 7
// 1538.371 us; speedup vs baseline: 1.7210x; 1.0211x over previous
//
#include <hip/hip_runtime.h>
#include <hip/hip_bf16.h>

#define NVOC 50257
#define DIM 256
#define HID 256
#define NLAYER 2
#define SEQ 128
#define BATCH 16
#define GUARD (1 << 20)

typedef __bf16 bf16x8 __attribute__((ext_vector_type(8)));
typedef float f32x4 __attribute__((ext_vector_type(4)));
typedef unsigned short u16;
typedef unsigned int u32;
typedef unsigned long long u64;

#define AL64(p)   __hip_atomic_load((const u64*)(p), __ATOMIC_RELAXED, __HIP_MEMORY_SCOPE_AGENT)
#define AS32(p,v) __hip_atomic_store((u32*)(p), (v), __ATOMIC_RELAXED, __HIP_MEMORY_SCOPE_AGENT)

__device__ __forceinline__ float fsig(float z) { return 1.f / (1.f + __expf(-z)); }
__device__ __forceinline__ float ftanh(float z) {
  const float x = fminf(fmaxf(z, -15.f), 15.f);
  const float e = __expf(2.f * x);
  return (e - 1.f) / (e + 1.f);
}
__device__ __forceinline__ bf16x8 cvt8(const float4 u0, const float4 u1) {
  bf16x8 v;
  v[0] = (__bf16)u0.x; v[1] = (__bf16)u0.y; v[2] = (__bf16)u0.z; v[3] = (__bf16)u0.w;
  v[4] = (__bf16)u1.x; v[5] = (__bf16)u1.y; v[6] = (__bf16)u1.z; v[7] = (__bf16)u1.w;
  return v;
}

// ---------------- prep: dec_w f32 -> bf16 ----------------
__global__ void prep_kernel(const float* __restrict__ dw, u16* __restrict__ dwb, int n4) {
  int tid = blockIdx.x * blockDim.x + threadIdx.x;
  int stride = gridDim.x * blockDim.x;
  for (int i = tid; i < n4; i += stride) {
    float4 v = reinterpret_cast<const float4*>(dw)[i];
    ushort4 o;
    o.x = __builtin_bit_cast(u16, (__bf16)v.x);
    o.y = __builtin_bit_cast(u16, (__bf16)v.y);
    o.z = __builtin_bit_cast(u16, (__bf16)v.z);
    o.w = __builtin_bit_cast(u16, (__bf16)v.w);
    reinterpret_cast<ushort4*>(dwb)[i] = o;
  }
}

// ---------------- XU precompute (bias folded in) + flag zero ----------------
// XU[t*16+b][g*256+c] = emb[tok[t,b]] @ U_g + b_g. Grid (32,4) x 256.
__global__ __launch_bounds__(256) void xu_kernel(
    const int* __restrict__ tokp, const float* __restrict__ embp,
    const float* __restrict__ uF, const float* __restrict__ uI,
    const float* __restrict__ uC, const float* __restrict__ uO,
    const float* __restrict__ bF, const float* __restrict__ bI,
    const float* __restrict__ bC, const float* __restrict__ bO,
    float* __restrict__ XU, u32* __restrict__ flg)
{
  const int tid = threadIdx.x;
  if (blockIdx.x == 0 && blockIdx.y == 0)
    for (int i = tid; i < SEQ * 4; i += 256) AS32(&flg[i], 0u);

  const int lane = tid & 63, wv = tid >> 6, r16 = lane & 15, kgrp = lane >> 4;
  const int m0 = blockIdx.x * 64;
  const int n0 = blockIdx.y * 256 + wv * 64;
  const float* Ug[4] = {uF, uI, uC, uO};
  const float* Bp[4] = {bF, bI, bC, bO};

  bf16x8 b[4][8];
  float bias[4];
#pragma unroll
  for (int nt = 0; nt < 4; ++nt) {
    const int n = n0 + nt * 16 + r16;
    const float* U = Ug[n >> 8];
    const int c = n & 255;
    bias[nt] = Bp[n >> 8][c];
#pragma unroll
    for (int kk = 0; kk < 8; ++kk) {
      const int kb = kk * 32 + kgrp * 8;
      bf16x8 v;
#pragma unroll
      for (int e = 0; e < 8; ++e) v[e] = (__bf16)U[(size_t)(kb + e) * HID + c];
      b[nt][kk] = v;
    }
  }

  for (int mi = 0; mi < 4; ++mi) {
    const int tok = tokp[m0 + mi * 16 + r16];
    const float* x = embp + (size_t)tok * DIM;
    bf16x8 a[8];
#pragma unroll
    for (int kk = 0; kk < 8; ++kk) {
      const int kb = kk * 32 + kgrp * 8;
      a[kk] = cvt8(*reinterpret_cast<const float4*>(x + kb),
                   *reinterpret_cast<const float4*>(x + kb + 4));
    }
#pragma unroll
    for (int nt = 0; nt < 4; ++nt) {
      f32x4 acc = {0.f, 0.f, 0.f, 0.f};
#pragma unroll
      for (int kk = 0; kk < 8; ++kk)
        acc = __builtin_amdgcn_mfma_f32_16x16x32_bf16(a[kk], b[nt][kk], acc, 0, 0, 0);
      const int n = n0 + nt * 16 + r16;
#pragma unroll
      for (int r = 0; r < 4; ++r)
        XU[(size_t)(m0 + mi * 16 + kgrp * 4 + r) * 1024 + n] = acc[r] + bias[nt];
    }
  }
}

// ---------------- persistent LSTM: 4 symmetric WGs, both layers each ----------------
// WG j owns cols [64j, 64j+64) of BOTH layers. Per step: compute h0-slice (K=256,
// XU precomputed) -> publish (packed u32 write-through atomics) -> one flag + one
// poll + acquire fence -> plain b128 load of full h0[t] AND full h1[t-1] (peers'
// h1 was published last step; same flag covers it) -> compute h1-slice (K=512).
// Only ONE cross-WG hop (h0) is on the serial critical path per step.
__global__ __launch_bounds__(256, 1) void lstm_kernel(
    const float* __restrict__ wF, const float* __restrict__ wI,
    const float* __restrict__ wC, const float* __restrict__ wO,
    const float* __restrict__ w1F, const float* __restrict__ w1I,
    const float* __restrict__ w1C, const float* __restrict__ w1O,
    const float* __restrict__ uF, const float* __restrict__ uI,
    const float* __restrict__ uC, const float* __restrict__ uO,
    const float* __restrict__ bF, const float* __restrict__ bI,
    const float* __restrict__ bC, const float* __restrict__ bO,
    const float* __restrict__ XU, u32* __restrict__ h0w, u32* __restrict__ h1w,
    u32* __restrict__ flg, float* __restrict__ dout)
{
  const int tid  = threadIdx.x;
  const int lane = tid & 63;
  const int wv   = tid >> 6;        // 0..3
  const int r16  = lane & 15;
  const int kgrp = lane >> 4;
  const int jj   = blockIdx.x;      // 0..3
  const int n    = jj * 64 + wv * 16 + r16;   // owned output col (both layers)

  const float* W0g[4] = {wF, wI, wC, wO};
  const float* W1g[4] = {w1F, w1I, w1C, w1O};
  const float* U1g[4] = {uF, uI, uC, uO};
  const float* B1g[4] = {bF, bI, bC, bO};
  const u16* h0s = (const u16*)h0w;
  const u16* h1s = (const u16*)h1w;
  const size_t logitsN = (size_t)SEQ * BATCH * NVOC;

  // ---- weight fragments in registers ----
  bf16x8 w0[4][8], w1[4][8], u1[4][8];
  float bias1[4];
#pragma unroll
  for (int g = 0; g < 4; ++g) {
    bias1[g] = B1g[g][n];
#pragma unroll
    for (int kk = 0; kk < 8; ++kk) {
      const int kb = kk * 32 + kgrp * 8;
      bf16x8 a, b, c;
#pragma unroll
      for (int e = 0; e < 8; ++e) {
        a[e] = (__bf16)W0g[g][(size_t)(kb + e) * HID + n];
        b[e] = (__bf16)W1g[g][(size_t)(kb + e) * HID + n];
        c[e] = (__bf16)U1g[g][(size_t)(kb + e) * HID + n];
      }
      w0[g][kk] = a; w1[g][kk] = b; u1[g][kk] = c;
    }
  }

  bf16x8 h0f[8], h1f[8];
  float c0st[4] = {0.f, 0.f, 0.f, 0.f};
  float c1st[4] = {0.f, 0.f, 0.f, 0.f};
  const int odd = lane & 1;
  const int npair = (n >> 1);       // u32 index of the (n&~1, n|1) pair

  for (int t = 0; t < SEQ; ++t) {
    // ======== phase A: layer-0 slice ========
    f32x4 acc0[4];
#pragma unroll
    for (int g = 0; g < 4; ++g) { acc0[g][0]=0.f; acc0[g][1]=0.f; acc0[g][2]=0.f; acc0[g][3]=0.f; }
    if (t > 0) {
#pragma unroll
      for (int kk = 0; kk < 8; ++kk)
#pragma unroll
        for (int g = 0; g < 4; ++g)
          acc0[g] = __builtin_amdgcn_mfma_f32_16x16x32_bf16(h0f[kk], w0[g][kk], acc0[g], 0, 0, 0);
    }

    const float* xp = XU + (size_t)t * BATCH * 1024;
    float hv0[4];
#pragma unroll
    for (int r = 0; r < 4; ++r) {
      const int b = kgrp * 4 + r;
      const float zf = acc0[0][r] + xp[(size_t)b * 1024 + n];
      const float zi = acc0[1][r] + xp[(size_t)b * 1024 + 256 + n];
      const float zg = acc0[2][r] + xp[(size_t)b * 1024 + 512 + n];
      const float zo = acc0[3][r] + xp[(size_t)b * 1024 + 768 + n];
      const float f = fsig(zf), i = fsig(zi), g = ftanh(zg), o = fsig(zo);
      c0st[r] = f * c0st[r] + i * g;
      hv0[r] = o * ftanh(c0st[r]);
    }
    // publish h0[t] slice: lane-pair packed u32 write-through stores
#pragma unroll
    for (int r = 0; r < 4; ++r) {
      const float ph = __shfl_xor(hv0[r], 1);
      const u16 a = __builtin_bit_cast(u16, (__bf16)hv0[r]);
      const u16 p = __builtin_bit_cast(u16, (__bf16)ph);
      const u32 pk = odd ? ((u32)p | ((u32)a << 16)) : ((u32)a | ((u32)p << 16));
      if ((r & 1) == odd)   // even lanes store r=0,2 ... split load evenly
        AS32(h0w + ((size_t)t * BATCH + kgrp * 4 + r) * 128 + npair, pk);
    }
    if (t == SEQ - 1) {
#pragma unroll
      for (int r = 0; r < 4; ++r) {
        const int b = kgrp * 4 + r;
        dout[logitsN + (size_t)b * HID + n] = hv0[r];
        dout[logitsN + (size_t)NLAYER * BATCH * HID + (size_t)b * HID + n] = c0st[r];
      }
    }
    __syncthreads();                        // drains h0[t] AND h1[t-1] stores
    if (tid == 0) {
      AS32(&flg[t * 4 + jj], 1u);           // my h0[t] + h1[t-1] visible
      int gd = 0;
      for (;;) {
        const u64 f0 = AL64(flg + t * 4);
        const u64 f1 = AL64(flg + t * 4 + 2);
        if (((u32)f0 & (u32)(f0 >> 32) & (u32)f1 & (u32)(f1 >> 32)) != 0u) break;
        if (++gd >= GUARD) break;
      }
    }
    __syncthreads();
    __builtin_amdgcn_fence(__ATOMIC_ACQUIRE, "agent");   // invalidate stale cache

    // ======== bulk loads: full h0[t], full h1[t-1] (plain b128) ========
    {
      const u16* hp = h0s + ((size_t)t * BATCH + r16) * HID + kgrp * 8;
#pragma unroll
      for (int kk = 0; kk < 8; ++kk)
        h0f[kk] = *reinterpret_cast<const bf16x8*>(hp + kk * 32);
    }
    if (t > 0) {
      const u16* hp = h1s + ((size_t)(t - 1) * BATCH + r16) * HID + kgrp * 8;
#pragma unroll
      for (int kk = 0; kk < 8; ++kk)
        h1f[kk] = *reinterpret_cast<const bf16x8*>(hp + kk * 32);
    }

    // ======== phase C: layer-1 slice (K=512) ========
    f32x4 acc1[4];
#pragma unroll
    for (int g = 0; g < 4; ++g) { acc1[g][0]=0.f; acc1[g][1]=0.f; acc1[g][2]=0.f; acc1[g][3]=0.f; }
#pragma unroll
    for (int kk = 0; kk < 8; ++kk)
#pragma unroll
      for (int g = 0; g < 4; ++g)
        acc1[g] = __builtin_amdgcn_mfma_f32_16x16x32_bf16(h0f[kk], u1[g][kk], acc1[g], 0, 0, 0);
    if (t > 0) {
#pragma unroll
      for (int kk = 0; kk < 8; ++kk)
#pragma unroll
        for (int g = 0; g < 4; ++g)
          acc1[g] = __builtin_amdgcn_mfma_f32_16x16x32_bf16(h1f[kk], w1[g][kk], acc1[g], 0, 0, 0);
    }

    float hv1[4];
#pragma unroll
    for (int r = 0; r < 4; ++r) {
      const float zf = acc1[0][r] + bias1[0];
      const float zi = acc1[1][r] + bias1[1];
      const float zg = acc1[2][r] + bias1[2];
      const float zo = acc1[3][r] + bias1[3];
      const float f = fsig(zf), i = fsig(zi), g = ftanh(zg), o = fsig(zo);
      c1st[r] = f * c1st[r] + i * g;
      hv1[r] = o * ftanh(c1st[r]);
    }
#pragma unroll
    for (int r = 0; r < 4; ++r) {
      const float ph = __shfl_xor(hv1[r], 1);
      const u16 a = __builtin_bit_cast(u16, (__bf16)hv1[r]);
      const u16 p = __builtin_bit_cast(u16, (__bf16)ph);
      const u32 pk = odd ? ((u32)p | ((u32)a << 16)) : ((u32)a | ((u32)p << 16));
      if ((r & 1) == odd)
        AS32(h1w + ((size_t)t * BATCH + kgrp * 4 + r) * 128 + npair, pk);
    }
    if (t == SEQ - 1) {
#pragma unroll
      for (int r = 0; r < 4; ++r) {
        const int b = kgrp * 4 + r;
        dout[logitsN + (size_t)(BATCH + b) * HID + n] = hv1[r];
        dout[logitsN + (size_t)NLAYER * BATCH * HID + (size_t)(BATCH + b) * HID + n] = c1st[r];
      }
    }
    // h1[t] stores drain at next iteration's __syncthreads, covered by flag[t+1].
  }
}

// ---------------- decoder (R2 shape): M=32/block, dec_w via L3 ----------------
__global__ __launch_bounds__(256) void dec_kernel(
    const u16* __restrict__ htb, const u16* __restrict__ dwb,
    const float* __restrict__ dbp, float* __restrict__ out)
{
  const int tid  = threadIdx.x;
  const int lane = tid & 63;
  const int wv   = tid >> 6;
  const int r16  = lane & 15;
  const int kgrp = lane >> 4;
  const int m0 = blockIdx.x * 32;
  const int n0 = blockIdx.y * 256 + wv * 64;

  bf16x8 a[2][8];
#pragma unroll
  for (int mt = 0; mt < 2; ++mt) {
    const u16* ap = htb + ((size_t)(m0 + mt * 16 + r16)) * HID + kgrp * 8;
#pragma unroll
    for (int kk = 0; kk < 8; ++kk)
      a[mt][kk] = *reinterpret_cast<const bf16x8*>(ap + kk * 32);
  }

  f32x4 acc[2][4];
#pragma unroll
  for (int mt = 0; mt < 2; ++mt)
#pragma unroll
    for (int nt = 0; nt < 4; ++nt) {
      acc[mt][nt][0] = 0.f; acc[mt][nt][1] = 0.f;
      acc[mt][nt][2] = 0.f; acc[mt][nt][3] = 0.f;
    }

#pragma unroll
  for (int nt = 0; nt < 4; ++nt) {
    const int v = n0 + nt * 16 + r16;
    const int vc = (v < NVOC) ? v : 0;
    const u16* bp = dwb + (size_t)vc * HID + kgrp * 8;
#pragma unroll
    for (int kk = 0; kk < 8; ++kk) {
      const bf16x8 b = *reinterpret_cast<const bf16x8*>(bp + kk * 32);
      acc[0][nt] = __builtin_amdgcn_mfma_f32_16x16x32_bf16(a[0][kk], b, acc[0][nt], 0, 0, 0);
      acc[1][nt] = __builtin_amdgcn_mfma_f32_16x16x32_bf16(a[1][kk], b, acc[1][nt], 0, 0, 0);
    }
  }

#pragma unroll
  for (int nt = 0; nt < 4; ++nt) {
    const int v = n0 + nt * 16 + r16;
    if (v < NVOC) {
      const float bb = dbp[v];
#pragma unroll
      for (int mt = 0; mt < 2; ++mt)
#pragma unroll
        for (int r = 0; r < 4; ++r)
          out[(size_t)(m0 + mt * 16 + kgrp * 4 + r) * NVOC + v] = acc[mt][nt][r] + bb;
    }
  }
}

extern "C" void kernel_launch(void* const* d_in, const int* in_sizes, int n_in,
                              void* d_out, int out_size, void* d_ws, size_t ws_size,
                              hipStream_t stream) {
  const int*   tokp = (const int*)d_in[0];
  const float* embp = (const float*)d_in[1];
  const float* wF = (const float*)d_in[2];
  const float* uF = (const float*)d_in[3];
  const float* bF = (const float*)d_in[4];
  const float* wI = (const float*)d_in[5];
  const float* uI = (const float*)d_in[6];
  const float* bI = (const float*)d_in[7];
  const float* wC = (const float*)d_in[8];
  const float* uC = (const float*)d_in[9];
  const float* bC = (const float*)d_in[10];
  const float* wO = (const float*)d_in[11];
  const float* uO = (const float*)d_in[12];
  const float* bO = (const float*)d_in[13];
  const float* dw = (const float*)d_in[14];
  const float* db = (const float*)d_in[15];
  float* out = (float*)d_out;

  char* ws = (char*)d_ws;
  size_t off = 0;
  char* regionA = ws;                           // XU (8 MB) aliased with dwb (25.7 MB)
  off += (size_t)NVOC * HID * 2;
  off = (off + 255) & ~(size_t)255;
  u32* h0w = (u32*)(ws + off); off += (size_t)SEQ * BATCH * HID * 2;   // bf16 h0
  u32* h1w = (u32*)(ws + off); off += (size_t)SEQ * BATCH * HID * 2;   // bf16 h1
  u32* flg = (u32*)(ws + off); off += (size_t)SEQ * 4 * 4;

  float* XU  = (float*)regionA;
  u16*   dwb = (u16*)regionA;

  // xu (writes XU with bias folded; atomically zeroes flg) -> lstm ->
  // prep (overwrites region A with dwb) -> dec (reads dwb, h1w)
  xu_kernel<<<dim3(32, 4), 256, 0, stream>>>(tokp, embp, uF, uI, uC, uO,
                                             bF, bI, bC, bO, XU, flg);
  lstm_kernel<<<4, 256, 0, stream>>>(wF, wI, wC, wO,
                                     wF, wI, wC, wO,   // layer-1 W (same params W*: see note)
                                     uF, uI, uC, uO,
                                     bF, bI, bC, bO,
                                     XU, h0w, h1w, flg, out);
  prep_kernel<<<1024, 256, 0, stream>>>(dw, dwb, NVOC * HID / 4);
  dec_kernel<<<dim3(64, (NVOC + 255) / 256), 256, 0, stream>>>((const u16*)h1w, dwb, db, out);
}

// Round 8
// 1221.128 us; speedup vs baseline: 2.1681x; 1.2598x over previous
//
#include <hip/hip_runtime.h>
#include <hip/hip_bf16.h>

#define NVOC 50257
#define DIM 256
#define HID 256
#define NLAYER 2
#define SEQ 128
#define BATCH 16
#define GUARD (1 << 20)

typedef __bf16 bf16x8 __attribute__((ext_vector_type(8)));
typedef float f32x4 __attribute__((ext_vector_type(4)));
typedef unsigned short u16;
typedef unsigned int u32;
typedef unsigned long long u64;

#define AL64(p)   __hip_atomic_load((const u64*)(p), __ATOMIC_RELAXED, __HIP_MEMORY_SCOPE_AGENT)
#define AS32(p,v) __hip_atomic_store((u32*)(p), (v), __ATOMIC_RELAXED, __HIP_MEMORY_SCOPE_AGENT)

__device__ __forceinline__ float fsig(float z) { return 1.f / (1.f + __expf(-z)); }
__device__ __forceinline__ float ftanh(float z) {
  const float x = fminf(fmaxf(z, -15.f), 15.f);
  const float e = __expf(2.f * x);
  return (e - 1.f) / (e + 1.f);
}
__device__ __forceinline__ bf16x8 cvt8(const float4 u0, const float4 u1) {
  bf16x8 v;
  v[0] = (__bf16)u0.x; v[1] = (__bf16)u0.y; v[2] = (__bf16)u0.z; v[3] = (__bf16)u0.w;
  v[4] = (__bf16)u1.x; v[5] = (__bf16)u1.y; v[6] = (__bf16)u1.z; v[7] = (__bf16)u1.w;
  return v;
}

// ---------------- prep: dec_w f32 -> bf16 ----------------
__global__ void prep_kernel(const float* __restrict__ dw, u16* __restrict__ dwb, int n4) {
  int tid = blockIdx.x * blockDim.x + threadIdx.x;
  int stride = gridDim.x * blockDim.x;
  for (int i = tid; i < n4; i += stride) {
    float4 v = reinterpret_cast<const float4*>(dw)[i];
    ushort4 o;
    o.x = __builtin_bit_cast(u16, (__bf16)v.x);
    o.y = __builtin_bit_cast(u16, (__bf16)v.y);
    o.z = __builtin_bit_cast(u16, (__bf16)v.z);
    o.w = __builtin_bit_cast(u16, (__bf16)v.w);
    reinterpret_cast<ushort4*>(dwb)[i] = o;
  }
}

// ---------------- XU precompute (layer-0 bias folded in) + flag zero ----------------
// XU[t*16+b][g*256+c] = emb[tok[t,b]] @ U_g + b_g. Grid (32,4) x 256.
__global__ __launch_bounds__(256) void xu_kernel(
    const int* __restrict__ tokp, const float* __restrict__ embp,
    const float* __restrict__ uF, const float* __restrict__ uI,
    const float* __restrict__ uC, const float* __restrict__ uO,
    const float* __restrict__ bF, const float* __restrict__ bI,
    const float* __restrict__ bC, const float* __restrict__ bO,
    float* __restrict__ XU, u32* __restrict__ flg)
{
  const int tid = threadIdx.x;
  if (blockIdx.x == 0 && blockIdx.y == 0)
    for (int i = tid; i < SEQ * 8; i += 256) AS32(&flg[i], 0u);

  const int lane = tid & 63, wv = tid >> 6, r16 = lane & 15, kgrp = lane >> 4;
  const int m0 = blockIdx.x * 64;
  const int n0 = blockIdx.y * 256 + wv * 64;
  const float* Ug[4] = {uF, uI, uC, uO};
  const float* Bp[4] = {bF, bI, bC, bO};

  bf16x8 b[4][8];
  float bias[4];
#pragma unroll
  for (int nt = 0; nt < 4; ++nt) {
    const int n = n0 + nt * 16 + r16;
    const float* U = Ug[n >> 8];
    const int c = n & 255;
    bias[nt] = Bp[n >> 8][c];
#pragma unroll
    for (int kk = 0; kk < 8; ++kk) {
      const int kb = kk * 32 + kgrp * 8;
      bf16x8 v;
#pragma unroll
      for (int e = 0; e < 8; ++e) v[e] = (__bf16)U[(size_t)(kb + e) * HID + c];
      b[nt][kk] = v;
    }
  }

  for (int mi = 0; mi < 4; ++mi) {
    const int tok = tokp[m0 + mi * 16 + r16];
    const float* x = embp + (size_t)tok * DIM;
    bf16x8 a[8];
#pragma unroll
    for (int kk = 0; kk < 8; ++kk) {
      const int kb = kk * 32 + kgrp * 8;
      a[kk] = cvt8(*reinterpret_cast<const float4*>(x + kb),
                   *reinterpret_cast<const float4*>(x + kb + 4));
    }
#pragma unroll
    for (int nt = 0; nt < 4; ++nt) {
      f32x4 acc = {0.f, 0.f, 0.f, 0.f};
#pragma unroll
      for (int kk = 0; kk < 8; ++kk)
        acc = __builtin_amdgcn_mfma_f32_16x16x32_bf16(a[kk], b[nt][kk], acc, 0, 0, 0);
      const int n = n0 + nt * 16 + r16;
#pragma unroll
      for (int r = 0; r < 4; ++r)
        XU[(size_t)(m0 + mi * 16 + kgrp * 4 + r) * 1024 + n] = acc[r] + bias[nt];
    }
  }
}

// ---------------- persistent LSTM: 8 WGs x 512 thr, no fences, no spills ----------------
// bx 0..3: layer 0 slice jj=bx   (cols [64jj,+64)), K=256 (x@U+b precomputed in XU).
// bx 4..7: layer 1 slice jj=bx-4 (cols [64jj,+64)), K=512 ([h1(t-1)@W ; h0(t)@U] + b).
// Wave wv (0..7): col-tile colt=wv&3 (16 cols), gate-pair gp=wv>>2 (gates 2gp,2gp+1)
//   -> weight frags/thread: L0 64 VGPR, L1 128 VGPR (fits 256 budget @ 2 waves/SIMD).
// Sync recipe (all R2/R6-proven): tid0-only atomic flag poll (GUARD-bounded, NO
// fence) -> barrier -> PLAIN b128 loads of h (cold lines) -> compute -> LDS gate
// combine -> packed-bf16 write-through atomic publish -> barrier (drains stores)
// -> tid0 atomic flag store. Layers pipelined: L0 never waits on L1.
__global__ __launch_bounds__(512, 1) void lstm_kernel(
    const float* __restrict__ wF, const float* __restrict__ wI,
    const float* __restrict__ wC, const float* __restrict__ wO,
    const float* __restrict__ uF, const float* __restrict__ uI,
    const float* __restrict__ uC, const float* __restrict__ uO,
    const float* __restrict__ bF, const float* __restrict__ bI,
    const float* __restrict__ bC, const float* __restrict__ bO,
    const float* __restrict__ XU, u32* __restrict__ h0w, u32* __restrict__ h1w,
    u32* __restrict__ flg, float* __restrict__ dout)
{
  const int tid  = threadIdx.x;
  const int lane = tid & 63;
  const int wv   = tid >> 6;        // 0..7
  const int r16  = lane & 15;
  const int kgrp = lane >> 4;
  const int colt = wv & 3;          // 16-col tile within the WG's 64 cols
  const int gp   = wv >> 2;         // gate pair: gates {2gp, 2gp+1}
  const int bx   = blockIdx.x;      // 0..7
  const int l    = bx >> 2;
  const int jj   = bx & 3;
  const int n    = jj * 64 + colt * 16 + r16;   // owned output col
  const int g0   = gp * 2;

  const float* Wg[4] = {wF, wI, wC, wO};
  const float* Ug[4] = {uF, uI, uC, uO};
  const float* Bg[4] = {bF, bI, bC, bO};
  const u16* h0s = (const u16*)h0w;
  const u16* h1s = (const u16*)h1w;
  const size_t logitsN = (size_t)SEQ * BATCH * NVOC;

  __shared__ float gbuf[4][16][72];

  // ---- weight fragments (registers) ----
  bf16x8 wa[2][8];   // L0: W (h0 recurrence); L1: W (h1(t-1) part)
  bf16x8 wb[2][8];   // L1 only: U (h0(t) part)
  float bias[2];
#pragma unroll
  for (int gi = 0; gi < 2; ++gi) {
    const int g = g0 + gi;
    bias[gi] = Bg[g][n];
#pragma unroll
    for (int kk = 0; kk < 8; ++kk) {
      const int kb = kk * 32 + kgrp * 8;
      bf16x8 v;
#pragma unroll
      for (int e = 0; e < 8; ++e) v[e] = (__bf16)Wg[g][(size_t)(kb + e) * HID + n];
      wa[gi][kk] = v;
      if (l == 1) {
        bf16x8 u;
#pragma unroll
        for (int e = 0; e < 8; ++e) u[e] = (__bf16)Ug[g][(size_t)(kb + e) * HID + n];
        wb[gi][kk] = u;
      }
    }
  }

  const int eb = tid >> 5;          // epilogue batch (16 x 32 threads)
  const int ec = (tid & 31) * 2;    // epilogue col pair within [0,64)
  float c0 = 0.f, c1 = 0.f;

  for (int t = 0; t < SEQ; ++t) {
    // ---- wait (tid0 only, no fence) ----
    if (tid == 0) {
      int gd = 0;
      if (l == 0) {
        if (t > 0)
          for (;;) {
            const u64 f0 = AL64(flg + (size_t)(t - 1) * 8);
            const u64 f1 = AL64(flg + (size_t)(t - 1) * 8 + 2);
            if (((u32)f0 & (u32)(f0 >> 32) & (u32)f1 & (u32)(f1 >> 32)) != 0u) break;
            if (++gd >= GUARD) break;
          }
      } else {
        for (;;) {
          const u64 f0 = AL64(flg + (size_t)t * 8);      // L0 @ t
          const u64 f1 = AL64(flg + (size_t)t * 8 + 2);
          u32 ok = (u32)f0 & (u32)(f0 >> 32) & (u32)f1 & (u32)(f1 >> 32);
          if (t > 0) {
            const u64 g1 = AL64(flg + (size_t)(t - 1) * 8 + 4);  // L1 peers @ t-1
            const u64 g2 = AL64(flg + (size_t)(t - 1) * 8 + 6);
            ok &= (u32)g1 & (u32)(g1 >> 32) & (u32)g2 & (u32)(g2 >> 32);
          }
          if (ok) break;
          if (++gd >= GUARD) break;
        }
      }
    }
    __syncthreads();

    // ---- plain b128 loads of h (cold lines, flag-gated) ----
    bf16x8 hA[8], hB[8];
    if (l == 0) {
      if (t > 0) {
        const u16* hp = h0s + ((size_t)(t - 1) * BATCH + r16) * HID + kgrp * 8;
#pragma unroll
        for (int kk = 0; kk < 8; ++kk)
          hA[kk] = *reinterpret_cast<const bf16x8*>(hp + kk * 32);
      }
    } else {
      const u16* xp = h0s + ((size_t)t * BATCH + r16) * HID + kgrp * 8;
#pragma unroll
      for (int kk = 0; kk < 8; ++kk)
        hA[kk] = *reinterpret_cast<const bf16x8*>(xp + kk * 32);
      if (t > 0) {
        const u16* hp = h1s + ((size_t)(t - 1) * BATCH + r16) * HID + kgrp * 8;
#pragma unroll
        for (int kk = 0; kk < 8; ++kk)
          hB[kk] = *reinterpret_cast<const bf16x8*>(hp + kk * 32);
      }
    }

    // ---- MFMA ----
    f32x4 acc[2];
#pragma unroll
    for (int gi = 0; gi < 2; ++gi) { acc[gi][0]=0.f; acc[gi][1]=0.f; acc[gi][2]=0.f; acc[gi][3]=0.f; }
    if (l == 0) {
      if (t > 0) {
#pragma unroll
        for (int kk = 0; kk < 8; ++kk)
#pragma unroll
          for (int gi = 0; gi < 2; ++gi)
            acc[gi] = __builtin_amdgcn_mfma_f32_16x16x32_bf16(hA[kk], wa[gi][kk], acc[gi], 0, 0, 0);
      }
    } else {
#pragma unroll
      for (int kk = 0; kk < 8; ++kk)
#pragma unroll
        for (int gi = 0; gi < 2; ++gi)
          acc[gi] = __builtin_amdgcn_mfma_f32_16x16x32_bf16(hA[kk], wb[gi][kk], acc[gi], 0, 0, 0);
      if (t > 0) {
#pragma unroll
        for (int kk = 0; kk < 8; ++kk)
#pragma unroll
          for (int gi = 0; gi < 2; ++gi)
            acc[gi] = __builtin_amdgcn_mfma_f32_16x16x32_bf16(hB[kk], wa[gi][kk], acc[gi], 0, 0, 0);
      }
    }

    // ---- activations -> LDS ----
#pragma unroll
    for (int gi = 0; gi < 2; ++gi) {
      const int g = g0 + gi;
#pragma unroll
      for (int r = 0; r < 4; ++r) {
        float z;
        if (l == 0)
          z = acc[gi][r] + XU[(size_t)(t * 16 + kgrp * 4 + r) * 1024 + g * 256 + n];
        else
          z = acc[gi][r] + bias[gi];
        gbuf[g][kgrp * 4 + r][colt * 16 + r16] = (g == 2) ? ftanh(z) : fsig(z);
      }
    }
    __syncthreads();

    // ---- c/h update (2 cols/thread) + packed publish ----
    const float ff0 = gbuf[0][eb][ec], ff1 = gbuf[0][eb][ec + 1];
    const float ii0 = gbuf[1][eb][ec], ii1 = gbuf[1][eb][ec + 1];
    const float gg0 = gbuf[2][eb][ec], gg1 = gbuf[2][eb][ec + 1];
    const float oo0 = gbuf[3][eb][ec], oo1 = gbuf[3][eb][ec + 1];
    c0 = ff0 * c0 + ii0 * gg0;
    c1 = ff1 * c1 + ii1 * gg1;
    const float hv0 = oo0 * ftanh(c0);
    const float hv1 = oo1 * ftanh(c1);
    const u32 pk = (u32)__builtin_bit_cast(u16, (__bf16)hv0) |
                   ((u32)__builtin_bit_cast(u16, (__bf16)hv1) << 16);
    u32* hw = l ? h1w : h0w;
    AS32(hw + ((size_t)t * BATCH + eb) * 128 + jj * 32 + (ec >> 1), pk);

    if (t == SEQ - 1) {
      const int nn = jj * 64 + ec;
      float* hT = dout + logitsN + ((size_t)l * BATCH + eb) * HID + nn;
      float* cT = dout + logitsN + (size_t)NLAYER * BATCH * HID + ((size_t)l * BATCH + eb) * HID + nn;
      hT[0] = hv0; hT[1] = hv1;
      cT[0] = c0;  cT[1] = c1;
    }
    __syncthreads();                // compiler emits vmcnt(0) drain before barrier
    if (tid == 0) AS32(&flg[(size_t)t * 8 + l * 4 + jj], 1u);
  }
}

// ---------------- decoder: M=64/block (dec_w traffic halved), full parallelism ----------------
// grid (32, 197). 4 waves; wave: 64 N-cols x 64 M-rows, K=256.
__global__ __launch_bounds__(256) void dec_kernel(
    const u16* __restrict__ htb, const u16* __restrict__ dwb,
    const float* __restrict__ dbp, float* __restrict__ out)
{
  const int tid  = threadIdx.x;
  const int lane = tid & 63;
  const int wv   = tid >> 6;
  const int r16  = lane & 15;
  const int kgrp = lane >> 4;
  const int m0 = blockIdx.x * 64;
  const int n0 = blockIdx.y * 256 + wv * 64;

  bf16x8 a[4][8];
#pragma unroll
  for (int mt = 0; mt < 4; ++mt) {
    const u16* ap = htb + ((size_t)(m0 + mt * 16 + r16)) * HID + kgrp * 8;
#pragma unroll
    for (int kk = 0; kk < 8; ++kk)
      a[mt][kk] = *reinterpret_cast<const bf16x8*>(ap + kk * 32);
  }

  f32x4 acc[4][4];
#pragma unroll
  for (int mt = 0; mt < 4; ++mt)
#pragma unroll
    for (int nt = 0; nt < 4; ++nt) {
      acc[mt][nt][0] = 0.f; acc[mt][nt][1] = 0.f;
      acc[mt][nt][2] = 0.f; acc[mt][nt][3] = 0.f;
    }

#pragma unroll
  for (int nt = 0; nt < 4; ++nt) {
    const int v = n0 + nt * 16 + r16;
    const int vc = (v < NVOC) ? v : 0;
    const u16* bp = dwb + (size_t)vc * HID + kgrp * 8;
#pragma unroll
    for (int kk = 0; kk < 8; ++kk) {
      const bf16x8 b = *reinterpret_cast<const bf16x8*>(bp + kk * 32);
#pragma unroll
      for (int mt = 0; mt < 4; ++mt)
        acc[mt][nt] = __builtin_amdgcn_mfma_f32_16x16x32_bf16(a[mt][kk], b, acc[mt][nt], 0, 0, 0);
    }
  }

#pragma unroll
  for (int nt = 0; nt < 4; ++nt) {
    const int v = n0 + nt * 16 + r16;
    if (v < NVOC) {
      const float bb = dbp[v];
#pragma unroll
      for (int mt = 0; mt < 4; ++mt)
#pragma unroll
        for (int r = 0; r < 4; ++r)
          out[(size_t)(m0 + mt * 16 + kgrp * 4 + r) * NVOC + v] = acc[mt][nt][r] + bb;
    }
  }
}

extern "C" void kernel_launch(void* const* d_in, const int* in_sizes, int n_in,
                              void* d_out, int out_size, void* d_ws, size_t ws_size,
                              hipStream_t stream) {
  const int*   tokp = (const int*)d_in[0];
  const float* embp = (const float*)d_in[1];
  const float* wF = (const float*)d_in[2];
  const float* uF = (const float*)d_in[3];
  const float* bF = (const float*)d_in[4];
  const float* wI = (const float*)d_in[5];
  const float* uI = (const float*)d_in[6];
  const float* bI = (const float*)d_in[7];
  const float* wC = (const float*)d_in[8];
  const float* uC = (const float*)d_in[9];
  const float* bC = (const float*)d_in[10];
  const float* wO = (const float*)d_in[11];
  const float* uO = (const float*)d_in[12];
  const float* bO = (const float*)d_in[13];
  const float* dw = (const float*)d_in[14];
  const float* db = (const float*)d_in[15];
  float* out = (float*)d_out;

  char* ws = (char*)d_ws;
  size_t off = 0;
  char* regionA = ws;                           // XU (8 MB) aliased with dwb (25.7 MB)
  off += (size_t)NVOC * HID * 2;
  off = (off + 255) & ~(size_t)255;
  u32* h0w = (u32*)(ws + off); off += (size_t)SEQ * BATCH * HID * 2;   // bf16 h0
  u32* h1w = (u32*)(ws + off); off += (size_t)SEQ * BATCH * HID * 2;   // bf16 h1
  u32* flg = (u32*)(ws + off); off += (size_t)SEQ * 8 * 4;

  float* XU  = (float*)regionA;
  u16*   dwb = (u16*)regionA;

  // xu (writes XU with L0 bias folded; atomically zeroes flg) -> lstm ->
  // prep (overwrites region A with dwb) -> dec (reads dwb, h1w)
  xu_kernel<<<dim3(32, 4), 256, 0, stream>>>(tokp, embp, uF, uI, uC, uO,
                                             bF, bI, bC, bO, XU, flg);
  lstm_kernel<<<8, 512, 0, stream>>>(wF, wI, wC, wO, uF, uI, uC, uO,
                                     bF, bI, bC, bO, XU, h0w, h1w, flg, out);
  prep_kernel<<<1024, 256, 0, stream>>>(dw, dwb, NVOC * HID / 4);
  dec_kernel<<<dim3(32, (NVOC + 255) / 256), 256, 0, stream>>>((const u16*)h1w, dwb, db, out);
}